// Round 6
// baseline (25405.461 us; speedup 1.0000x reference)
//
#include <hip/hip_runtime.h>

#define NWG   256
#define TPB   256
#define Bsz   128
#define Tlen  512
#define Pn    10
#define In    50
#define Hn    512
#define Cn    8
#define KTOT  562          // 512 (h) + 50 (emb)
#define KPAD  576          // padded; 144 float4 (multiple of 8 for XOR swizzle)
#define KF4   144
#define BSL   32           // batch rows per group
#define GRPW  64           // j-WGs per batch group

// ---- workspace layout (floats) ----
#define OFF_H   1024                   // u32[0..255]: 4 groups x 64 arrival flags
#define HBUF_N  (2*Bsz*Hn)
#define OFF_S   (OFF_H + HBUF_N)
#define SROW    12
#define SBUF_N  (3*Bsz*SROW)
#define WS_FLOATS (OFF_S + SBUF_N)

// ---- LDS layout (floats) ---- (identical to R3)
#define L_SW     0                     // [32][KPAD] gate rows (swizzled)
#define L_SH     (32*KPAD)             // [32][KPAD] [h | emb | pad] (swizzled)
#define L_SCR    (2*32*KPAD)           // 3072: attn[32*10] | partialsT[3*16*64] | u[32*51]
#define L_SWA    (L_SCR + 3072)        // [8][51], col 50 = ba
#define L_BIAS   (L_SWA + 408)         // [32]
#define L_HNEW   (L_BIAS + 32)         // [8][33]  hnew[jj][b]
#define LDS_FLOATS (L_HNEW + 264)      // 40640 floats = 162560 B
#define LDS_BYTES  (LDS_FLOATS*4)

extern "C" __global__ void __launch_bounds__(TPB, 1) fused_att_lstm(
    const float* __restrict__ x,   const float* __restrict__ mask,
    const float* __restrict__ Wa,  const float* __restrict__ ba,
    const float* __restrict__ Wih, const float* __restrict__ Whh,
    const float* __restrict__ bih, const float* __restrict__ bhh,
    const float* __restrict__ Wfc, const float* __restrict__ bfc,
    float* __restrict__ out, float* __restrict__ ws)
{
  extern __shared__ __align__(16) float lds[];
  float* sW    = lds + L_SW;
  float* sH    = lds + L_SH;
  float* sScr  = lds + L_SCR;    // attn / partialsT / u (disjoint lifetimes)
  float* sWa   = lds + L_SWA;
  float* sBias = lds + L_BIAS;
  float* sHnew = lds + L_HNEW;

  const int tid = threadIdx.x;
  const int wg  = blockIdx.x;
  const int jw  = wg & 63;
  const int grp = wg >> 6;
  const int bG0 = grp * BSL;
  const int jG0 = jw * 8;

  unsigned* flags = reinterpret_cast<unsigned*>(ws) + grp*64;
  float* hbuf = ws + OFF_H;        // [2][B][H]
  float* Sbuf = ws + OFF_S;        // [3][B][SROW]

  // ---- load resident weights (swizzled store: f4idx ^= (row>>2)&7) ----
  for (int idx = tid; idx < 32*KPAD; idx += TPB) {
    int r = idx / KPAD, k = idx - r*KPAD;
    int jj = r >> 2, g = r & 3;
    int grow = g*Hn + jG0 + jj;    // torch gate order i,f,g,o
    float v = 0.f;
    if (k < Hn)        v = Whh[grow*Hn + k];
    else if (k < KTOT) v = Wih[grow*In + (k - Hn)];
    sW[r*KPAD + (((((k>>2) ^ ((r>>2)&7))) << 2) | (k & 3))] = v;
  }
  for (int idx = tid; idx < 8*51; idx += TPB) {
    int jj = idx / 51, i = idx - jj*51;
    sWa[idx] = (i < In) ? Wa[(jG0+jj)*In + i] : ba[jG0+jj];
  }
  if (tid < 32) {
    int jj = tid >> 2, g = tid & 3;
    int grow = g*Hn + jG0 + jj;
    sBias[tid] = bih[grow] + bhh[grow];
  }
  if (tid < 32) {                          // zero pad cols 562..575 of sH once
    for (int k = KTOT; k < KPAD; ++k)
      sH[tid*KPAD + (((((k>>2) ^ ((tid>>2)&7))) << 2) | (k & 3))] = 0.f;
  }
  __syncthreads();

  const int kg = tid >> 6;                 // k-split group (wave index)
  const int tb = (tid >> 3) & 7;           // batch-tile (4 rows: 4tb..4tb+3)
  const int tr = tid & 7;                  // gate-row tile (rows 4tr..4tr+3 = jj=tr)
  const int lane = tid & 63;
  float cr[4] = {0.f, 0.f, 0.f, 0.f};      // cell state (kg0 threads: 4 cells)
  unsigned bgen = 0;

  for (int t = 0; t < Tlen; ++t) {
    const float* hprev = hbuf + ((t+1)&1)*Bsz*Hn;
    float*       hcur  = hbuf + (t&1)*Bsz*Hn;
    const float* Scur  = Sbuf + (t%3)*Bsz*SROW;
    float*       Snext = Sbuf + ((t+1)%3)*Bsz*SROW;
    float*       Szero = Sbuf + ((t+2)%3)*Bsz*SROW;

    // ---- A: stage h (swizzled), zero future score slice, softmax ----
    {
      const float4* src = reinterpret_cast<const float4*>(hprev) + (size_t)bG0*(Hn/4);
      float4* dst = reinterpret_cast<float4*>(sH);
      #pragma unroll
      for (int it = 0; it < 16; ++it) {
        int f = it*TPB + tid;
        int b = f >> 7, kf = f & 127;
        dst[b*KF4 + (kf ^ ((b>>2)&7))] = src[b*(Hn/4) + kf];
      }
    }
    if (tid < 6) Szero[bG0*SROW + jw*6 + tid] = 0.f;

    if (tid < BSL) {
      int bG = bG0 + tid;
      const float* srow = Scur + (size_t)bG*SROW;
      const float* mrow = mask + ((size_t)bG*Tlen + t)*Pn*In;
      float sc[Pn]; float mx = -1e30f;
      #pragma unroll
      for (int p = 0; p < Pn; ++p) {
        float s = srow[p];
        s = (mrow[p*In] > 0.f) ? s : -1e9f;
        sc[p] = s; mx = fmaxf(mx, s);
      }
      float den = 0.f;
      #pragma unroll
      for (int p = 0; p < Pn; ++p) { sc[p] = expf(sc[p] - mx); den += sc[p]; }
      float inv = 1.f / den;
      #pragma unroll
      for (int p = 0; p < Pn; ++p) sScr[tid*10 + p] = sc[p] * inv;  // attn
    }
    __syncthreads();

    // ---- B: emb[b,i] -> sH cols 512..561 (swizzled scalar store) ----
    for (int idx = tid; idx < BSL*In; idx += TPB) {
      int b = idx / In, ic = idx - b*In;
      const float* xb = x + (((size_t)(bG0+b)*Tlen + t)*Pn)*In + ic;
      float e = 0.f;
      #pragma unroll
      for (int p = 0; p < Pn; ++p) e = fmaf(sScr[b*10+p], xb[p*In], e);
      int k = Hn + ic;
      sH[b*KPAD + (((((k>>2) ^ ((b>>2)&7))) << 2) | (k & 3))] = e;
    }
    __syncthreads();

    // ---- C: gate GEMM 32x32, 4-way k-split, 4x4 tiles, conflict-free ----
    float acc[4][4];
    {
      #pragma unroll
      for (int i = 0; i < 4; ++i)
        #pragma unroll
        for (int j = 0; j < 4; ++j) acc[i][j] = 0.f;
      const float4* sH4 = reinterpret_cast<const float4*>(sH);
      const float4* sW4 = reinterpret_cast<const float4*>(sW);
      const int kbeg = kg*36, kend = kbeg + 36;
      for (int kc = kbeg; kc < kend; ++kc) {
        float4 hv[4], wv[4];
        #pragma unroll
        for (int i = 0; i < 4; ++i) hv[i] = sH4[(4*tb+i)*KF4 + (kc ^ tb)];
        #pragma unroll
        for (int j = 0; j < 4; ++j) wv[j] = sW4[(4*tr+j)*KF4 + (kc ^ tr)];
        #pragma unroll
        for (int i = 0; i < 4; ++i)
          #pragma unroll
          for (int j = 0; j < 4; ++j) {
            acc[i][j] = fmaf(hv[i].x, wv[j].x, acc[i][j]);
            acc[i][j] = fmaf(hv[i].y, wv[j].y, acc[i][j]);
            acc[i][j] = fmaf(hv[i].z, wv[j].z, acc[i][j]);
            acc[i][j] = fmaf(hv[i].w, wv[j].w, acc[i][j]);
          }
      }
      if (kg > 0) {                        // transposed partials: stride-4B lanes
        float* dst = sScr + (kg-1)*1024 + lane;
        #pragma unroll
        for (int q = 0; q < 16; ++q) dst[q*64] = acc[q>>2][q&3];
      }
    }
    __syncthreads();

    // ---- D: kg0 reduces partials + LSTM cells (c in registers) ----
    if (kg == 0) {
      #pragma unroll
      for (int i = 0; i < 4; ++i) {
        float gv[4];
        #pragma unroll
        for (int g = 0; g < 4; ++g) {
          int q = i*4 + g;
          float v = acc[i][g];
          v += sScr[0*1024 + q*64 + lane];
          v += sScr[1*1024 + q*64 + lane];
          v += sScr[2*1024 + q*64 + lane];
          gv[g] = v + sBias[4*tr + g];
        }
        float ig = 1.f/(1.f + expf(-gv[0]));
        float fg = 1.f/(1.f + expf(-gv[1]));
        float gc = tanhf(gv[2]);
        float og = 1.f/(1.f + expf(-gv[3]));
        cr[i] = fg*cr[i] + ig*gc;
        float hn = og * tanhf(cr[i]);
        int b = 4*tb + i;
        sHnew[tr*33 + b] = hn;
        hcur[(size_t)(bG0+b)*Hn + jG0 + tr] = hn;
      }
    }
    __syncthreads();

    // ---- E1: partial u[b,i] = sum_jj Wa[jj,i]*hnew[b,jj]  (col 50 = ba.h) ----
    if (t < Tlen-1) {
      for (int idx = tid; idx < BSL*51; idx += TPB) {
        int b = idx / 51, ic = idx - b*51;
        float v = 0.f;
        #pragma unroll
        for (int jj = 0; jj < 8; ++jj) v = fmaf(sWa[jj*51+ic], sHnew[jj*33+b], v);
        sScr[idx] = v;                     // u overlays partials (lifetime ok)
      }
    }
    __syncthreads();

    // ---- E2: partial scores s[b,p] = u50 + x_{t+1}.u ; 320 atomics/WG ----
    if (t < Tlen-1) {
      for (int pr = tid; pr < BSL*Pn; pr += TPB) {
        int b = pr / Pn, p = pr - b*Pn;
        const float2* xp = reinterpret_cast<const float2*>(
            x + (((size_t)(bG0+b)*Tlen + (t+1))*Pn + p)*In);
        const float* u = sScr + b*51;
        float s = u[50];
        #pragma unroll
        for (int k2 = 0; k2 < 25; ++k2) {
          float2 xv = xp[k2];
          s = fmaf(xv.x, u[2*k2],   s);
          s = fmaf(xv.y, u[2*k2+1], s);
        }
        atomicAdd(&Snext[(size_t)(bG0+b)*SROW + p], s);
      }
    }

    // ---- hardened flag-array group barrier (ONLY change vs R3) ----
    ++bgen;
    __syncthreads();                       // all waves arrive
    __threadfence();                       // each wave: drain + wb L2
    __syncthreads();                       // all writebacks done
    if (tid == 0)
      __hip_atomic_store(&flags[jw], bgen, __ATOMIC_RELEASE, __HIP_MEMORY_SCOPE_AGENT);
    if (tid < GRPW) {
      for (;;) {
        unsigned f = __hip_atomic_load(&flags[tid], __ATOMIC_RELAXED, __HIP_MEMORY_SCOPE_AGENT);
        if (__all(f >= bgen)) break;
        __builtin_amdgcn_s_sleep(2);
      }
    }
    __syncthreads();                       // wave0's observation covers WG
    __threadfence();                       // acquire: invalidate before reads
  }

  // ---- final classifier (jw==0 WG of each group) ----
  if (jw == 0) {
    const float* hfin = hbuf + ((Tlen-1)&1)*Bsz*Hn;
    int b = tid >> 3, cc = tid & 7;
    int bG = bG0 + b;
    const float4* hv = reinterpret_cast<const float4*>(hfin + (size_t)bG*Hn);
    const float4* wv = reinterpret_cast<const float4*>(Wfc + cc*Hn);
    float s0=0,s1=0,s2=0,s3=0;
    #pragma unroll 4
    for (int k = 0; k < Hn/4; ++k) {
      float4 a = hv[k], w = wv[k];
      s0 = fmaf(a.x,w.x,s0); s1 = fmaf(a.y,w.y,s1);
      s2 = fmaf(a.z,w.z,s2); s3 = fmaf(a.w,w.w,s3);
    }
    out[bG*Cn + cc] = (s0+s1)+(s2+s3) + bfc[cc];
  }
}

extern "C" void kernel_launch(void* const* d_in, const int* in_sizes, int n_in,
                              void* d_out, int out_size, void* d_ws, size_t ws_size,
                              hipStream_t stream) {
  const float* x    = (const float*)d_in[0];
  const float* mask = (const float*)d_in[1];
  const float* Wa   = (const float*)d_in[2];
  const float* ba   = (const float*)d_in[3];
  const float* Wih  = (const float*)d_in[4];
  const float* Whh  = (const float*)d_in[5];
  const float* bih  = (const float*)d_in[6];
  const float* bhh  = (const float*)d_in[7];
  const float* Wfc  = (const float*)d_in[8];
  const float* bfc  = (const float*)d_in[9];
  float* out = (float*)d_out;
  float* ws  = (float*)d_ws;

  // reset flags + h/score buffers every launch (deterministic replay)
  hipMemsetAsync(d_ws, 0, (size_t)WS_FLOATS * sizeof(float), stream);

  (void)hipFuncSetAttribute((const void*)fused_att_lstm,
                            hipFuncAttributeMaxDynamicSharedMemorySize, LDS_BYTES);

  void* args[] = { (void*)&x, (void*)&mask, (void*)&Wa, (void*)&ba,
                   (void*)&Wih, (void*)&Whh, (void*)&bih, (void*)&bhh,
                   (void*)&Wfc, (void*)&bfc, (void*)&out, (void*)&ws };
  hipLaunchCooperativeKernel((void*)fused_att_lstm, dim3(NWG), dim3(TPB),
                             args, LDS_BYTES, stream);
}

// Round 7
// 16113.202 us; speedup vs baseline: 1.5767x; 1.5767x over previous
//
#include <hip/hip_runtime.h>

typedef unsigned long long ull;

#define NWG   256
#define TPB   256
#define Bsz   128
#define Tlen  512
#define Pn    10
#define In    50
#define Hn    512
#define Cn    8
#define KTOT  562          // 512 (h) + 50 (emb)
#define KPAD  576          // padded; 144 float4 (multiple of 8 for XOR swizzle)
#define KF4   144
#define BSL   32           // batch rows per group
#define GRPW  64           // j-WGs per batch group

// coherent (agent-scope, relaxed) access helpers: compile to sc0/sc1 loads/stores
// that bypass L1/L2 and hit the coherence point directly -> no fences needed.
#define AL(p)    __hip_atomic_load((p),  __ATOMIC_RELAXED, __HIP_MEMORY_SCOPE_AGENT)
#define AS(p,v)  __hip_atomic_store((p), (v), __ATOMIC_RELAXED, __HIP_MEMORY_SCOPE_AGENT)

// ---- workspace layout (floats) ----
#define OFF_H   1024                   // u32[0..255]: 4 groups x 64 arrival flags
#define HBUF_N  (2*Bsz*Hn)
#define OFF_S   (OFF_H + HBUF_N)
#define SROW    12
#define SBUF_N  (3*Bsz*SROW)
#define WS_FLOATS (OFF_S + SBUF_N)

// ---- LDS layout (floats) ---- (identical to R3/R6)
#define L_SW     0                     // [32][KPAD] gate rows (swizzled)
#define L_SH     (32*KPAD)             // [32][KPAD] [h | emb | pad] (swizzled)
#define L_SCR    (2*32*KPAD)           // 3072: attn[32*10] | partialsT[3*16*64] | u[32*51]
#define L_SWA    (L_SCR + 3072)        // [8][51], col 50 = ba
#define L_BIAS   (L_SWA + 408)         // [32]
#define L_HNEW   (L_BIAS + 32)         // [8][33]  hnew[jj][b]
#define LDS_FLOATS (L_HNEW + 264)      // 40640 floats = 162560 B
#define LDS_BYTES  (LDS_FLOATS*4)

union UF2 { ull u; float2 f; };

extern "C" __global__ void __launch_bounds__(TPB, 1) fused_att_lstm(
    const float* __restrict__ x,   const float* __restrict__ mask,
    const float* __restrict__ Wa,  const float* __restrict__ ba,
    const float* __restrict__ Wih, const float* __restrict__ Whh,
    const float* __restrict__ bih, const float* __restrict__ bhh,
    const float* __restrict__ Wfc, const float* __restrict__ bfc,
    float* __restrict__ out, float* __restrict__ ws)
{
  extern __shared__ __align__(16) float lds[];
  float* sW    = lds + L_SW;
  float* sH    = lds + L_SH;
  float* sScr  = lds + L_SCR;    // attn / partialsT / u (disjoint lifetimes)
  float* sWa   = lds + L_SWA;
  float* sBias = lds + L_BIAS;
  float* sHnew = lds + L_HNEW;

  const int tid = threadIdx.x;
  const int wg  = blockIdx.x;
  const int jw  = wg & 63;
  const int grp = wg >> 6;
  const int bG0 = grp * BSL;
  const int jG0 = jw * 8;

  unsigned* flags = reinterpret_cast<unsigned*>(ws) + grp*64;
  float* hbuf = ws + OFF_H;        // [2][B][H]
  float* Sbuf = ws + OFF_S;        // [3][B][SROW]

  // ---- load resident weights (swizzled store: f4idx ^= (row>>2)&7) ----
  for (int idx = tid; idx < 32*KPAD; idx += TPB) {
    int r = idx / KPAD, k = idx - r*KPAD;
    int jj = r >> 2, g = r & 3;
    int grow = g*Hn + jG0 + jj;    // torch gate order i,f,g,o
    float v = 0.f;
    if (k < Hn)        v = Whh[grow*Hn + k];
    else if (k < KTOT) v = Wih[grow*In + (k - Hn)];
    sW[r*KPAD + (((((k>>2) ^ ((r>>2)&7))) << 2) | (k & 3))] = v;
  }
  for (int idx = tid; idx < 8*51; idx += TPB) {
    int jj = idx / 51, i = idx - jj*51;
    sWa[idx] = (i < In) ? Wa[(jG0+jj)*In + i] : ba[jG0+jj];
  }
  if (tid < 32) {
    int jj = tid >> 2, g = tid & 3;
    int grow = g*Hn + jG0 + jj;
    sBias[tid] = bih[grow] + bhh[grow];
  }
  if (tid < 32) {                          // zero pad cols 562..575 of sH once
    for (int k = KTOT; k < KPAD; ++k)
      sH[tid*KPAD + (((((k>>2) ^ ((tid>>2)&7))) << 2) | (k & 3))] = 0.f;
  }
  __syncthreads();

  const int kg = tid >> 6;                 // k-split group (wave index)
  const int tb = (tid >> 3) & 7;           // batch-tile (4 rows: 4tb..4tb+3)
  const int tr = tid & 7;                  // gate-row tile (rows 4tr..4tr+3 = jj=tr)
  const int lane = tid & 63;
  float cr[4] = {0.f, 0.f, 0.f, 0.f};      // cell state (kg0 threads: 4 cells)
  unsigned bgen = 0;

  for (int t = 0; t < Tlen; ++t) {
    const float* hprev = hbuf + ((t+1)&1)*Bsz*Hn;
    float*       hcur  = hbuf + (t&1)*Bsz*Hn;
    const float* Scur  = Sbuf + (t%3)*Bsz*SROW;
    float*       Snext = Sbuf + ((t+1)%3)*Bsz*SROW;
    float*       Szero = Sbuf + ((t+2)%3)*Bsz*SROW;

    // ---- A: stage h via coherent 8B loads (swizzled), zero slice, softmax ----
    {
      const ull* src = reinterpret_cast<const ull*>(hprev + (size_t)bG0*Hn);
      #pragma unroll
      for (int it = 0; it < 32; ++it) {
        int f = it*TPB + tid;              // 0..8191 (32 rows x 256 ull)
        int b = f >> 8, kd = f & 255;
        UF2 cv; cv.u = AL(&src[b*256 + kd]);
        int kf = kd >> 1;
        int fi = b*KPAD + (((kf ^ ((b>>2)&7))) << 2) + (kd & 1)*2;
        *reinterpret_cast<float2*>(&sH[fi]) = cv.f;
      }
    }
    if (tid < 6) AS(&Szero[bG0*SROW + jw*6 + tid], 0.f);

    if (tid < BSL) {
      int bG = bG0 + tid;
      const float* srow = Scur + (size_t)bG*SROW;
      const float* mrow = mask + ((size_t)bG*Tlen + t)*Pn*In;
      float sc[Pn]; float mx = -1e30f;
      #pragma unroll
      for (int p = 0; p < Pn; ++p) {
        float s = AL(&srow[p]);
        s = (mrow[p*In] > 0.f) ? s : -1e9f;
        sc[p] = s; mx = fmaxf(mx, s);
      }
      float den = 0.f;
      #pragma unroll
      for (int p = 0; p < Pn; ++p) { sc[p] = expf(sc[p] - mx); den += sc[p]; }
      float inv = 1.f / den;
      #pragma unroll
      for (int p = 0; p < Pn; ++p) sScr[tid*10 + p] = sc[p] * inv;  // attn
    }
    __syncthreads();

    // ---- B: emb[b,i] -> sH cols 512..561 (swizzled scalar store) ----
    for (int idx = tid; idx < BSL*In; idx += TPB) {
      int b = idx / In, ic = idx - b*In;
      const float* xb = x + (((size_t)(bG0+b)*Tlen + t)*Pn)*In + ic;
      float e = 0.f;
      #pragma unroll
      for (int p = 0; p < Pn; ++p) e = fmaf(sScr[b*10+p], xb[p*In], e);
      int k = Hn + ic;
      sH[b*KPAD + (((((k>>2) ^ ((b>>2)&7))) << 2) | (k & 3))] = e;
    }
    __syncthreads();

    // ---- C: gate GEMM 32x32, 4-way k-split, 4x4 tiles, conflict-free ----
    float acc[4][4];
    {
      #pragma unroll
      for (int i = 0; i < 4; ++i)
        #pragma unroll
        for (int j = 0; j < 4; ++j) acc[i][j] = 0.f;
      const float4* sH4 = reinterpret_cast<const float4*>(sH);
      const float4* sW4 = reinterpret_cast<const float4*>(sW);
      const int kbeg = kg*36, kend = kbeg + 36;
      for (int kc = kbeg; kc < kend; ++kc) {
        float4 hv[4], wv[4];
        #pragma unroll
        for (int i = 0; i < 4; ++i) hv[i] = sH4[(4*tb+i)*KF4 + (kc ^ tb)];
        #pragma unroll
        for (int j = 0; j < 4; ++j) wv[j] = sW4[(4*tr+j)*KF4 + (kc ^ tr)];
        #pragma unroll
        for (int i = 0; i < 4; ++i)
          #pragma unroll
          for (int j = 0; j < 4; ++j) {
            acc[i][j] = fmaf(hv[i].x, wv[j].x, acc[i][j]);
            acc[i][j] = fmaf(hv[i].y, wv[j].y, acc[i][j]);
            acc[i][j] = fmaf(hv[i].z, wv[j].z, acc[i][j]);
            acc[i][j] = fmaf(hv[i].w, wv[j].w, acc[i][j]);
          }
      }
      if (kg > 0) {                        // transposed partials: stride-4B lanes
        float* dst = sScr + (kg-1)*1024 + lane;
        #pragma unroll
        for (int q = 0; q < 16; ++q) dst[q*64] = acc[q>>2][q&3];
      }
    }
    __syncthreads();

    // ---- D: kg0 reduces partials + LSTM cells (c in registers) ----
    if (kg == 0) {
      #pragma unroll
      for (int i = 0; i < 4; ++i) {
        float gv[4];
        #pragma unroll
        for (int g = 0; g < 4; ++g) {
          int q = i*4 + g;
          float v = acc[i][g];
          v += sScr[0*1024 + q*64 + lane];
          v += sScr[1*1024 + q*64 + lane];
          v += sScr[2*1024 + q*64 + lane];
          gv[g] = v + sBias[4*tr + g];
        }
        float ig = 1.f/(1.f + expf(-gv[0]));
        float fg = 1.f/(1.f + expf(-gv[1]));
        float gc = tanhf(gv[2]);
        float og = 1.f/(1.f + expf(-gv[3]));
        cr[i] = fg*cr[i] + ig*gc;
        float hn = og * tanhf(cr[i]);
        int b = 4*tb + i;
        sHnew[tr*33 + b] = hn;
        AS(&hcur[(size_t)(bG0+b)*Hn + jG0 + tr], hn);   // coherent store
      }
    }
    __syncthreads();

    // ---- E1: partial u[b,i] = sum_jj Wa[jj,i]*hnew[b,jj]  (col 50 = ba.h) ----
    if (t < Tlen-1) {
      for (int idx = tid; idx < BSL*51; idx += TPB) {
        int b = idx / 51, ic = idx - b*51;
        float v = 0.f;
        #pragma unroll
        for (int jj = 0; jj < 8; ++jj) v = fmaf(sWa[jj*51+ic], sHnew[jj*33+b], v);
        sScr[idx] = v;                     // u overlays partials (lifetime ok)
      }
    }
    __syncthreads();

    // ---- E2: partial scores s[b,p] = u50 + x_{t+1}.u ; 320 atomics/WG ----
    if (t < Tlen-1) {
      for (int pr = tid; pr < BSL*Pn; pr += TPB) {
        int b = pr / Pn, p = pr - b*Pn;
        const float2* xp = reinterpret_cast<const float2*>(
            x + (((size_t)(bG0+b)*Tlen + (t+1))*Pn + p)*In);
        const float* u = sScr + b*51;
        float s = u[50];
        #pragma unroll
        for (int k2 = 0; k2 < 25; ++k2) {
          float2 xv = xp[k2];
          s = fmaf(xv.x, u[2*k2],   s);
          s = fmaf(xv.y, u[2*k2+1], s);
        }
        atomicAdd(&Snext[(size_t)(bG0+b)*SROW + p], s);
      }
    }

    // ---- fence-free flag barrier: all cross-WG data is coherence-point ----
    ++bgen;
    __syncthreads();               // compiler emits s_waitcnt vmcnt(0) before
                                   // s_barrier: every wave's sc1 stores/atomics
                                   // have reached the coherence point here.
    if (tid == 0) AS(&flags[jw], bgen);
    __builtin_amdgcn_sched_barrier(0);   // keep store before poll (compile-time)
    if (tid < GRPW) {
      for (;;) {
        unsigned f = AL(&flags[tid]);
        if (__all(f >= bgen)) break;
        __builtin_amdgcn_s_sleep(2);
      }
    }
    __syncthreads();               // wave0's observation covers the WG
  }

  // ---- final classifier (jw==0 WG of each group), coherent h reads ----
  if (jw == 0) {
    const float* hfin = hbuf + ((Tlen-1)&1)*Bsz*Hn;
    int b = tid >> 3, cc = tid & 7;
    int bG = bG0 + b;
    const ull* hv = reinterpret_cast<const ull*>(hfin + (size_t)bG*Hn);
    const float2* wv = reinterpret_cast<const float2*>(Wfc + cc*Hn);
    float s0 = 0.f, s1 = 0.f;
    #pragma unroll 8
    for (int k = 0; k < Hn/2; ++k) {
      UF2 cv; cv.u = AL(&hv[k]);
      float2 w = wv[k];
      s0 = fmaf(cv.f.x, w.x, s0); s1 = fmaf(cv.f.y, w.y, s1);
    }
    out[bG*Cn + cc] = s0 + s1 + bfc[cc];
  }
}

extern "C" void kernel_launch(void* const* d_in, const int* in_sizes, int n_in,
                              void* d_out, int out_size, void* d_ws, size_t ws_size,
                              hipStream_t stream) {
  const float* x    = (const float*)d_in[0];
  const float* mask = (const float*)d_in[1];
  const float* Wa   = (const float*)d_in[2];
  const float* ba   = (const float*)d_in[3];
  const float* Wih  = (const float*)d_in[4];
  const float* Whh  = (const float*)d_in[5];
  const float* bih  = (const float*)d_in[6];
  const float* bhh  = (const float*)d_in[7];
  const float* Wfc  = (const float*)d_in[8];
  const float* bfc  = (const float*)d_in[9];
  float* out = (float*)d_out;
  float* ws  = (float*)d_ws;

  // reset flags + h/score buffers every launch (deterministic replay)
  hipMemsetAsync(d_ws, 0, (size_t)WS_FLOATS * sizeof(float), stream);

  (void)hipFuncSetAttribute((const void*)fused_att_lstm,
                            hipFuncAttributeMaxDynamicSharedMemorySize, LDS_BYTES);

  void* args[] = { (void*)&x, (void*)&mask, (void*)&Wa, (void*)&ba,
                   (void*)&Wih, (void*)&Whh, (void*)&bih, (void*)&bhh,
                   (void*)&Wfc, (void*)&bfc, (void*)&out, (void*)&ws };
  hipLaunchCooperativeKernel((void*)fused_att_lstm, dim3(NWG), dim3(TPB),
                             args, LDS_BYTES, stream);
}

// Round 8
// 14032.956 us; speedup vs baseline: 1.8104x; 1.1482x over previous
//
#include <hip/hip_runtime.h>

#define NWG   256
#define TPB   256
#define Bsz   128
#define Tlen  512
#define Pn    10
#define In    50
#define Hn    512
#define Cn    8
#define KTOT  562          // 512 (h) + 50 (emb)
#define KPAD  576          // padded; 144 float4 (multiple of 8 for XOR swizzle)
#define KF4   144
#define BSL   32           // batch rows per group
#define GRPW  64           // j-WGs per batch group

// ---- workspace layout (floats) ----
#define OFF_H   1024                   // u32[0..255]: 4 groups x 64 arrival flags
#define HBUF_N  (2*Bsz*Hn)
#define OFF_S   (OFF_H + HBUF_N)
#define SROW    12
#define SBUF_N  (3*Bsz*SROW)
#define WS_FLOATS (OFF_S + SBUF_N)

// ---- LDS layout (floats) ---- (identical to R3/R6)
#define L_SW     0                     // [32][KPAD] gate rows (swizzled)
#define L_SH     (32*KPAD)             // [32][KPAD] [h | emb | pad] (swizzled)
#define L_SCR    (2*32*KPAD)           // 3072: attn[32*10] | partialsT[3*16*64] | u[32*51]
#define L_SWA    (L_SCR + 3072)        // [8][51], col 50 = ba
#define L_BIAS   (L_SWA + 408)         // [32]
#define L_HNEW   (L_BIAS + 32)         // [8][33]  hnew[jj][b]
#define LDS_FLOATS (L_HNEW + 264)      // 40640 floats = 162560 B
#define LDS_BYTES  (LDS_FLOATS*4)

extern "C" __global__ void __launch_bounds__(TPB, 1) fused_att_lstm(
    const float* __restrict__ x,   const float* __restrict__ mask,
    const float* __restrict__ Wa,  const float* __restrict__ ba,
    const float* __restrict__ Wih, const float* __restrict__ Whh,
    const float* __restrict__ bih, const float* __restrict__ bhh,
    const float* __restrict__ Wfc, const float* __restrict__ bfc,
    float* __restrict__ out, float* __restrict__ ws)
{
  extern __shared__ __align__(16) float lds[];
  float* sW    = lds + L_SW;
  float* sH    = lds + L_SH;
  float* sScr  = lds + L_SCR;    // attn / partialsT / u (disjoint lifetimes)
  float* sWa   = lds + L_SWA;
  float* sBias = lds + L_BIAS;
  float* sHnew = lds + L_HNEW;

  const int tid = threadIdx.x;
  const int wg  = blockIdx.x;
  const int jw  = wg & 63;
  const int grp = wg >> 6;
  const int bG0 = grp * BSL;
  const int jG0 = jw * 8;

  unsigned* flags = reinterpret_cast<unsigned*>(ws) + grp*64;
  float* hbuf = ws + OFF_H;        // [2][B][H]
  float* Sbuf = ws + OFF_S;        // [3][B][SROW]

  // ---- load resident weights (swizzled store: f4idx ^= (row>>2)&7) ----
  for (int idx = tid; idx < 32*KPAD; idx += TPB) {
    int r = idx / KPAD, k = idx - r*KPAD;
    int jj = r >> 2, g = r & 3;
    int grow = g*Hn + jG0 + jj;    // torch gate order i,f,g,o
    float v = 0.f;
    if (k < Hn)        v = Whh[grow*Hn + k];
    else if (k < KTOT) v = Wih[grow*In + (k - Hn)];
    sW[r*KPAD + (((((k>>2) ^ ((r>>2)&7))) << 2) | (k & 3))] = v;
  }
  for (int idx = tid; idx < 8*51; idx += TPB) {
    int jj = idx / 51, i = idx - jj*51;
    sWa[idx] = (i < In) ? Wa[(jG0+jj)*In + i] : ba[jG0+jj];
  }
  if (tid < 32) {
    int jj = tid >> 2, g = tid & 3;
    int grow = g*Hn + jG0 + jj;
    sBias[tid] = bih[grow] + bhh[grow];
  }
  if (tid < 32) {                          // zero pad cols 562..575 of sH once
    for (int k = KTOT; k < KPAD; ++k)
      sH[tid*KPAD + (((((k>>2) ^ ((tid>>2)&7))) << 2) | (k & 3))] = 0.f;
  }
  __syncthreads();

  const int kg = tid >> 6;                 // k-split group (wave index)
  const int tb = (tid >> 3) & 7;           // batch-tile (4 rows: 4tb..4tb+3)
  const int tr = tid & 7;                  // gate-row tile (rows 4tr..4tr+3 = jj=tr)
  const int lane = tid & 63;
  float cr[4] = {0.f, 0.f, 0.f, 0.f};      // cell state (kg0 threads: 4 cells)
  unsigned bgen = 0;

  for (int t = 0; t < Tlen; ++t) {
    const float* hprev = hbuf + ((t+1)&1)*Bsz*Hn;
    float*       hcur  = hbuf + (t&1)*Bsz*Hn;
    const float* Scur  = Sbuf + (t%3)*Bsz*SROW;
    float*       Snext = Sbuf + ((t+1)%3)*Bsz*SROW;
    float*       Szero = Sbuf + ((t+2)%3)*Bsz*SROW;

    // ---- A: stage h (swizzled), zero future score slice, softmax ----
    {
      const float4* src = reinterpret_cast<const float4*>(hprev) + (size_t)bG0*(Hn/4);
      float4* dst = reinterpret_cast<float4*>(sH);
      #pragma unroll
      for (int it = 0; it < 16; ++it) {
        int f = it*TPB + tid;
        int b = f >> 7, kf = f & 127;
        dst[b*KF4 + (kf ^ ((b>>2)&7))] = src[b*(Hn/4) + kf];
      }
    }
    if (tid < 6) Szero[bG0*SROW + jw*6 + tid] = 0.f;

    if (tid < BSL) {
      int bG = bG0 + tid;
      const float* srow = Scur + (size_t)bG*SROW;
      const float* mrow = mask + ((size_t)bG*Tlen + t)*Pn*In;
      float sc[Pn]; float mx = -1e30f;
      #pragma unroll
      for (int p = 0; p < Pn; ++p) {
        float s = srow[p];
        s = (mrow[p*In] > 0.f) ? s : -1e9f;
        sc[p] = s; mx = fmaxf(mx, s);
      }
      float den = 0.f;
      #pragma unroll
      for (int p = 0; p < Pn; ++p) { sc[p] = expf(sc[p] - mx); den += sc[p]; }
      float inv = 1.f / den;
      #pragma unroll
      for (int p = 0; p < Pn; ++p) sScr[tid*10 + p] = sc[p] * inv;  // attn
    }
    __syncthreads();

    // ---- B: emb[b,i] -> sH cols 512..561 (swizzled scalar store) ----
    for (int idx = tid; idx < BSL*In; idx += TPB) {
      int b = idx / In, ic = idx - b*In;
      const float* xb = x + (((size_t)(bG0+b)*Tlen + t)*Pn)*In + ic;
      float e = 0.f;
      #pragma unroll
      for (int p = 0; p < Pn; ++p) e = fmaf(sScr[b*10+p], xb[p*In], e);
      int k = Hn + ic;
      sH[b*KPAD + (((((k>>2) ^ ((b>>2)&7))) << 2) | (k & 3))] = e;
    }
    __syncthreads();

    // ---- C: gate GEMM 32x32, 4-way k-split, 4x4 tiles, conflict-free ----
    float acc[4][4];
    {
      #pragma unroll
      for (int i = 0; i < 4; ++i)
        #pragma unroll
        for (int j = 0; j < 4; ++j) acc[i][j] = 0.f;
      const float4* sH4 = reinterpret_cast<const float4*>(sH);
      const float4* sW4 = reinterpret_cast<const float4*>(sW);
      const int kbeg = kg*36, kend = kbeg + 36;
      for (int kc = kbeg; kc < kend; ++kc) {
        float4 hv[4], wv[4];
        #pragma unroll
        for (int i = 0; i < 4; ++i) hv[i] = sH4[(4*tb+i)*KF4 + (kc ^ tb)];
        #pragma unroll
        for (int j = 0; j < 4; ++j) wv[j] = sW4[(4*tr+j)*KF4 + (kc ^ tr)];
        #pragma unroll
        for (int i = 0; i < 4; ++i)
          #pragma unroll
          for (int j = 0; j < 4; ++j) {
            acc[i][j] = fmaf(hv[i].x, wv[j].x, acc[i][j]);
            acc[i][j] = fmaf(hv[i].y, wv[j].y, acc[i][j]);
            acc[i][j] = fmaf(hv[i].z, wv[j].z, acc[i][j]);
            acc[i][j] = fmaf(hv[i].w, wv[j].w, acc[i][j]);
          }
      }
      if (kg > 0) {                        // transposed partials: stride-4B lanes
        float* dst = sScr + (kg-1)*1024 + lane;
        #pragma unroll
        for (int q = 0; q < 16; ++q) dst[q*64] = acc[q>>2][q&3];
      }
    }
    __syncthreads();

    // ---- D: kg0 reduces partials + LSTM cells (c in registers) ----
    if (kg == 0) {
      #pragma unroll
      for (int i = 0; i < 4; ++i) {
        float gv[4];
        #pragma unroll
        for (int g = 0; g < 4; ++g) {
          int q = i*4 + g;
          float v = acc[i][g];
          v += sScr[0*1024 + q*64 + lane];
          v += sScr[1*1024 + q*64 + lane];
          v += sScr[2*1024 + q*64 + lane];
          gv[g] = v + sBias[4*tr + g];
        }
        float ig = 1.f/(1.f + expf(-gv[0]));
        float fg = 1.f/(1.f + expf(-gv[1]));
        float gc = tanhf(gv[2]);
        float og = 1.f/(1.f + expf(-gv[3]));
        cr[i] = fg*cr[i] + ig*gc;
        float hn = og * tanhf(cr[i]);
        int b = 4*tb + i;
        sHnew[tr*33 + b] = hn;
        hcur[(size_t)(bG0+b)*Hn + jG0 + tr] = hn;
      }
    }
    __syncthreads();

    // ---- E1: partial u[b,i] = sum_jj Wa[jj,i]*hnew[b,jj]  (col 50 = ba.h) ----
    if (t < Tlen-1) {
      for (int idx = tid; idx < BSL*51; idx += TPB) {
        int b = idx / 51, ic = idx - b*51;
        float v = 0.f;
        #pragma unroll
        for (int jj = 0; jj < 8; ++jj) v = fmaf(sWa[jj*51+ic], sHnew[jj*33+b], v);
        sScr[idx] = v;                     // u overlays partials (lifetime ok)
      }
    }
    __syncthreads();

    // ---- E2: partial scores s[b,p] = u50 + x_{t+1}.u ; 320 atomics/WG ----
    if (t < Tlen-1) {
      for (int pr = tid; pr < BSL*Pn; pr += TPB) {
        int b = pr / Pn, p = pr - b*Pn;
        const float2* xp = reinterpret_cast<const float2*>(
            x + (((size_t)(bG0+b)*Tlen + (t+1))*Pn + p)*In);
        const float* u = sScr + b*51;
        float s = u[50];
        #pragma unroll
        for (int k2 = 0; k2 < 25; ++k2) {
          float2 xv = xp[k2];
          s = fmaf(xv.x, u[2*k2],   s);
          s = fmaf(xv.y, u[2*k2+1], s);
        }
        atomicAdd(&Snext[(size_t)(bG0+b)*SROW + p], s);
      }
    }

    // ---- barrier: R3 fence discipline (2 tid0 fences), flag-array arrival ----
    ++bgen;
    __syncthreads();                       // all waves' phase writes vmcnt-drained
    if (tid == 0) {
      __threadfence();                     // release: wb this XCD's L2 (covers all waves)
      __hip_atomic_store(&flags[jw], bgen, __ATOMIC_RELEASE, __HIP_MEMORY_SCOPE_AGENT);
    }
    if (tid < GRPW) {                      // wave0 (fence+store done first, lockstep)
      for (;;) {
        unsigned f = __hip_atomic_load(&flags[tid], __ATOMIC_RELAXED, __HIP_MEMORY_SCOPE_AGENT);
        if (__all(f >= bgen)) break;
        __builtin_amdgcn_s_sleep(2);
      }
    }
    __syncthreads();                       // gate all waves on wave0's detection
    if (tid == 0) __threadfence();         // acquire: invalidate L1/L2
    __syncthreads();                       // gate reads on invalidate completion
  }

  // ---- final classifier (jw==0 WG of each group) ----
  if (jw == 0) {
    const float* hfin = hbuf + ((Tlen-1)&1)*Bsz*Hn;
    int b = tid >> 3, cc = tid & 7;
    int bG = bG0 + b;
    const float4* hv = reinterpret_cast<const float4*>(hfin + (size_t)bG*Hn);
    const float4* wv = reinterpret_cast<const float4*>(Wfc + cc*Hn);
    float s0=0,s1=0,s2=0,s3=0;
    #pragma unroll 4
    for (int k = 0; k < Hn/4; ++k) {
      float4 a = hv[k], w = wv[k];
      s0 = fmaf(a.x,w.x,s0); s1 = fmaf(a.y,w.y,s1);
      s2 = fmaf(a.z,w.z,s2); s3 = fmaf(a.w,w.w,s3);
    }
    out[bG*Cn + cc] = (s0+s1)+(s2+s3) + bfc[cc];
  }
}

extern "C" void kernel_launch(void* const* d_in, const int* in_sizes, int n_in,
                              void* d_out, int out_size, void* d_ws, size_t ws_size,
                              hipStream_t stream) {
  const float* x    = (const float*)d_in[0];
  const float* mask = (const float*)d_in[1];
  const float* Wa   = (const float*)d_in[2];
  const float* ba   = (const float*)d_in[3];
  const float* Wih  = (const float*)d_in[4];
  const float* Whh  = (const float*)d_in[5];
  const float* bih  = (const float*)d_in[6];
  const float* bhh  = (const float*)d_in[7];
  const float* Wfc  = (const float*)d_in[8];
  const float* bfc  = (const float*)d_in[9];
  float* out = (float*)d_out;
  float* ws  = (float*)d_ws;

  // reset flags + h/score buffers every launch (deterministic replay)
  hipMemsetAsync(d_ws, 0, (size_t)WS_FLOATS * sizeof(float), stream);

  (void)hipFuncSetAttribute((const void*)fused_att_lstm,
                            hipFuncAttributeMaxDynamicSharedMemorySize, LDS_BYTES);

  void* args[] = { (void*)&x, (void*)&mask, (void*)&Wa, (void*)&ba,
                   (void*)&Wih, (void*)&Whh, (void*)&bih, (void*)&bhh,
                   (void*)&Wfc, (void*)&bfc, (void*)&out, (void*)&ws };
  hipLaunchCooperativeKernel((void*)fused_att_lstm, dim3(NWG), dim3(TPB),
                             args, LDS_BYTES, stream);
}

// Round 9
// 11270.471 us; speedup vs baseline: 2.2542x; 1.2451x over previous
//
#include <hip/hip_runtime.h>

#define NWG   256
#define TPB   256
#define Bsz   128
#define Tlen  512
#define Pn    10
#define In    50
#define Hn    512
#define Cn    8
#define KTOT  562          // 512 (h) + 50 (emb)
#define KPAD  576          // padded; 144 float4 (multiple of 8 for XOR swizzle)
#define KF4   144
#define BSL   32           // batch rows per group
#define GRPW  64           // j-WGs per batch group

// sc-coherent (agent-scope relaxed) accessors: write-through / read-through the
// coherence point, bypassing the non-coherent L1/L2 (R7-proven correct).
#define AS(p,v)  __hip_atomic_store((p), (v), __ATOMIC_RELAXED, __HIP_MEMORY_SCOPE_AGENT)
#define ALU(p)   __hip_atomic_load((p),  __ATOMIC_RELAXED, __HIP_MEMORY_SCOPE_AGENT)

// ---- workspace layout (floats) ----
#define OFF_H   1024                   // u32[0..255]: 4 groups x {cnt, gen}
#define HBUF_N  (2*Bsz*Hn)
#define OFF_S   (OFF_H + HBUF_N)
#define SROW    12
#define SBUF_N  (3*Bsz*SROW)
#define WS_FLOATS (OFF_S + SBUF_N)

// ---- LDS layout (floats) ---- (identical to R3)
#define L_SW     0                     // [32][KPAD] gate rows (swizzled)
#define L_SH     (32*KPAD)             // [32][KPAD] [h | emb | pad] (swizzled)
#define L_SCR    (2*32*KPAD)           // 3072: attn[32*10] | partialsT[3*16*64] | u[32*51]
#define L_SWA    (L_SCR + 3072)        // [8][51], col 50 = ba
#define L_BIAS   (L_SWA + 408)         // [32]
#define L_HNEW   (L_BIAS + 32)         // [8][33]  hnew[jj][b]
#define LDS_FLOATS (L_HNEW + 264)      // 40640 floats = 162560 B
#define LDS_BYTES  (LDS_FLOATS*4)

extern "C" __global__ void __launch_bounds__(TPB, 1) fused_att_lstm(
    const float* __restrict__ x,   const float* __restrict__ mask,
    const float* __restrict__ Wa,  const float* __restrict__ ba,
    const float* __restrict__ Wih, const float* __restrict__ Whh,
    const float* __restrict__ bih, const float* __restrict__ bhh,
    const float* __restrict__ Wfc, const float* __restrict__ bfc,
    float* __restrict__ out, float* __restrict__ ws)
{
  extern __shared__ __align__(16) float lds[];
  float* sW    = lds + L_SW;
  float* sH    = lds + L_SH;
  float* sScr  = lds + L_SCR;    // attn / partialsT / u (disjoint lifetimes)
  float* sWa   = lds + L_SWA;
  float* sBias = lds + L_BIAS;
  float* sHnew = lds + L_HNEW;

  const int tid = threadIdx.x;
  const int wg  = blockIdx.x;
  const int jw  = wg & 63;
  const int grp = wg >> 6;
  const int bG0 = grp * BSL;
  const int jG0 = jw * 8;

  unsigned* cnt = reinterpret_cast<unsigned*>(ws) + grp*64;
  unsigned* gen = cnt + 16;
  float* hbuf = ws + OFF_H;        // [2][B][H]
  float* Sbuf = ws + OFF_S;        // [3][B][SROW]

  // ---- load resident weights (swizzled store: f4idx ^= (row>>2)&7) ----
  for (int idx = tid; idx < 32*KPAD; idx += TPB) {
    int r = idx / KPAD, k = idx - r*KPAD;
    int jj = r >> 2, g = r & 3;
    int grow = g*Hn + jG0 + jj;    // torch gate order i,f,g,o
    float v = 0.f;
    if (k < Hn)        v = Whh[grow*Hn + k];
    else if (k < KTOT) v = Wih[grow*In + (k - Hn)];
    sW[r*KPAD + (((((k>>2) ^ ((r>>2)&7))) << 2) | (k & 3))] = v;
  }
  for (int idx = tid; idx < 8*51; idx += TPB) {
    int jj = idx / 51, i = idx - jj*51;
    sWa[idx] = (i < In) ? Wa[(jG0+jj)*In + i] : ba[jG0+jj];
  }
  if (tid < 32) {
    int jj = tid >> 2, g = tid & 3;
    int grow = g*Hn + jG0 + jj;
    sBias[tid] = bih[grow] + bhh[grow];
  }
  if (tid < 32) {                          // zero pad cols 562..575 of sH once
    for (int k = KTOT; k < KPAD; ++k)
      sH[tid*KPAD + (((((k>>2) ^ ((tid>>2)&7))) << 2) | (k & 3))] = 0.f;
  }
  __syncthreads();

  const int kg = tid >> 6;                 // k-split group (wave index)
  const int tb = (tid >> 3) & 7;           // batch-tile (4 rows: 4tb..4tb+3)
  const int tr = tid & 7;                  // gate-row tile (rows 4tr..4tr+3 = jj=tr)
  const int lane = tid & 63;
  float cr[4] = {0.f, 0.f, 0.f, 0.f};      // cell state (kg0 threads: 4 cells)
  unsigned bgen = 0;

  for (int t = 0; t < Tlen; ++t) {
    const float* hprev = hbuf + ((t+1)&1)*Bsz*Hn;
    float*       hcur  = hbuf + (t&1)*Bsz*Hn;
    const float* Scur  = Sbuf + (t%3)*Bsz*SROW;
    float*       Snext = Sbuf + ((t+1)%3)*Bsz*SROW;
    float*       Szero = Sbuf + ((t+2)%3)*Bsz*SROW;

    // ---- A: stage h (swizzled); early softmax loads; hoist B's x loads ----
    {
      const float4* src = reinterpret_cast<const float4*>(hprev) + (size_t)bG0*(Hn/4);
      float4* dst = reinterpret_cast<float4*>(sH);
      #pragma unroll
      for (int it = 0; it < 16; ++it) {
        int f = it*TPB + tid;
        int b = f >> 7, kf = f & 127;
        dst[b*KF4 + (kf ^ ((b>>2)&7))] = src[b*(Hn/4) + kf];
      }
    }
    // softmax inputs issued FIRST so their vmcnt wait excludes the x-hoist
    float sreg[Pn], mreg[Pn];
    if (tid < BSL) {
      const float* srow = Scur + (size_t)(bG0+tid)*SROW;
      const float* mrow = mask + ((size_t)(bG0+tid)*Tlen + t)*Pn*In;
      #pragma unroll
      for (int p = 0; p < Pn; ++p) { sreg[p] = srow[p]; mreg[p] = mrow[p*In]; }
    }
    if (tid < 6) AS(&Szero[bG0*SROW + jw*6 + tid], 0.f);

    // hoisted B-phase x loads (identical addresses/order as R3's B loop)
    float xh0[Pn], xh1[Pn], xh2[Pn], xh3[Pn], xh4[Pn], xh5[Pn], xh6[Pn];
#define HOIST(S, ARR) { int idx = tid + (S)*TPB; if (idx < BSL*In) {            \
      int b = idx / In, ic = idx - b*In;                                        \
      const float* xb = x + (((size_t)(bG0+b)*Tlen + t)*Pn)*In + ic;            \
      _Pragma("unroll") for (int p = 0; p < Pn; ++p) ARR[p] = xb[p*In]; } }
    HOIST(0, xh0) HOIST(1, xh1) HOIST(2, xh2) HOIST(3, xh3)
    HOIST(4, xh4) HOIST(5, xh5) HOIST(6, xh6)
#undef HOIST

    if (tid < BSL) {
      float sc[Pn]; float mx = -1e30f;
      #pragma unroll
      for (int p = 0; p < Pn; ++p) {
        float s = sreg[p];
        s = (mreg[p] > 0.f) ? s : -1e9f;
        sc[p] = s; mx = fmaxf(mx, s);
      }
      float den = 0.f;
      #pragma unroll
      for (int p = 0; p < Pn; ++p) { sc[p] = expf(sc[p] - mx); den += sc[p]; }
      float inv = 1.f / den;
      #pragma unroll
      for (int p = 0; p < Pn; ++p) sScr[tid*10 + p] = sc[p] * inv;  // attn
    }
    __syncthreads();

    // ---- B: emb[b,i] from hoisted regs (same FMA order as R3) ----
#define BTASK(S, ARR) { int idx = tid + (S)*TPB; if (idx < BSL*In) {            \
      int b = idx / In, ic = idx - b*In;                                        \
      float e = 0.f;                                                            \
      _Pragma("unroll") for (int p = 0; p < Pn; ++p)                            \
        e = fmaf(sScr[b*10+p], ARR[p], e);                                      \
      int k = Hn + ic;                                                          \
      sH[b*KPAD + (((((k>>2) ^ ((b>>2)&7))) << 2) | (k & 3))] = e; } }
    BTASK(0, xh0) BTASK(1, xh1) BTASK(2, xh2) BTASK(3, xh3)
    BTASK(4, xh4) BTASK(5, xh5) BTASK(6, xh6)
#undef BTASK
    __syncthreads();

    // ---- C: gate GEMM 32x32, 4-way k-split, 4x4 tiles, conflict-free ----
    float acc[4][4];
    {
      #pragma unroll
      for (int i = 0; i < 4; ++i)
        #pragma unroll
        for (int j = 0; j < 4; ++j) acc[i][j] = 0.f;
      const float4* sH4 = reinterpret_cast<const float4*>(sH);
      const float4* sW4 = reinterpret_cast<const float4*>(sW);
      const int kbeg = kg*36, kend = kbeg + 36;
      for (int kc = kbeg; kc < kend; ++kc) {
        float4 hv[4], wv[4];
        #pragma unroll
        for (int i = 0; i < 4; ++i) hv[i] = sH4[(4*tb+i)*KF4 + (kc ^ tb)];
        #pragma unroll
        for (int j = 0; j < 4; ++j) wv[j] = sW4[(4*tr+j)*KF4 + (kc ^ tr)];
        #pragma unroll
        for (int i = 0; i < 4; ++i)
          #pragma unroll
          for (int j = 0; j < 4; ++j) {
            acc[i][j] = fmaf(hv[i].x, wv[j].x, acc[i][j]);
            acc[i][j] = fmaf(hv[i].y, wv[j].y, acc[i][j]);
            acc[i][j] = fmaf(hv[i].z, wv[j].z, acc[i][j]);
            acc[i][j] = fmaf(hv[i].w, wv[j].w, acc[i][j]);
          }
      }
      if (kg > 0) {                        // transposed partials: stride-4B lanes
        float* dst = sScr + (kg-1)*1024 + lane;
        #pragma unroll
        for (int q = 0; q < 16; ++q) dst[q*64] = acc[q>>2][q&3];
      }
    }
    __syncthreads();

    // ---- D: kg0 reduces partials + LSTM cells (c in registers) ----
    if (kg == 0) {
      #pragma unroll
      for (int i = 0; i < 4; ++i) {
        float gv[4];
        #pragma unroll
        for (int g = 0; g < 4; ++g) {
          int q = i*4 + g;
          float v = acc[i][g];
          v += sScr[0*1024 + q*64 + lane];
          v += sScr[1*1024 + q*64 + lane];
          v += sScr[2*1024 + q*64 + lane];
          gv[g] = v + sBias[4*tr + g];
        }
        float ig = 1.f/(1.f + expf(-gv[0]));
        float fg = 1.f/(1.f + expf(-gv[1]));
        float gc = tanhf(gv[2]);
        float og = 1.f/(1.f + expf(-gv[3]));
        cr[i] = fg*cr[i] + ig*gc;
        float hn = og * tanhf(cr[i]);
        int b = 4*tb + i;
        sHnew[tr*33 + b] = hn;
        AS(&hcur[(size_t)(bG0+b)*Hn + jG0 + tr], hn);   // sc store -> no release fence
      }
    }
    __syncthreads();

    // ---- E1: partial u[b,i] = sum_jj Wa[jj,i]*hnew[b,jj]  (col 50 = ba.h) ----
    if (t < Tlen-1) {
      for (int idx = tid; idx < BSL*51; idx += TPB) {
        int b = idx / 51, ic = idx - b*51;
        float v = 0.f;
        #pragma unroll
        for (int jj = 0; jj < 8; ++jj) v = fmaf(sWa[jj*51+ic], sHnew[jj*33+b], v);
        sScr[idx] = v;                     // u overlays partials (lifetime ok)
      }
    }
    __syncthreads();

    // ---- E2: partial scores s[b,p] = u50 + x_{t+1}.u ; 320 atomics/WG ----
    if (t < Tlen-1) {
      for (int pr = tid; pr < BSL*Pn; pr += TPB) {
        int b = pr / Pn, p = pr - b*Pn;
        const float2* xp = reinterpret_cast<const float2*>(
            x + (((size_t)(bG0+b)*Tlen + (t+1))*Pn + p)*In);
        const float* u = sScr + b*51;
        float s = u[50];
        #pragma unroll
        for (int k2 = 0; k2 < 25; ++k2) {
          float2 xv = xp[k2];
          s = fmaf(xv.x, u[2*k2],   s);
          s = fmaf(xv.y, u[2*k2+1], s);
        }
        atomicAdd(&Snext[(size_t)(bG0+b)*SROW + p], s);
      }
    }

    // ---- counter barrier, release-fence-free (sc stores already at MALL) ----
    ++bgen;
    __syncthreads();                       // all waves vmcnt-drained => sc data visible
    if (tid == 0) {
      unsigned old = atomicAdd(cnt, 1u);   // arrival (device-scope RMW at MALL)
      if (old == bgen * (unsigned)GRPW - 1u) {
        AS(gen, bgen);
      } else {
        while (ALU(gen) < bgen) __builtin_amdgcn_s_sleep(2);
      }
      __threadfence();                     // acquire: invalidate L1/L2 for cached reads
    }
    __syncthreads();
  }

  // ---- final classifier (jw==0 WG of each group) ----
  if (jw == 0) {
    const float* hfin = hbuf + ((Tlen-1)&1)*Bsz*Hn;
    int b = tid >> 3, cc = tid & 7;
    int bG = bG0 + b;
    const float4* hv = reinterpret_cast<const float4*>(hfin + (size_t)bG*Hn);
    const float4* wv = reinterpret_cast<const float4*>(Wfc + cc*Hn);
    float s0=0,s1=0,s2=0,s3=0;
    #pragma unroll 4
    for (int k = 0; k < Hn/4; ++k) {
      float4 a = hv[k], w = wv[k];
      s0 = fmaf(a.x,w.x,s0); s1 = fmaf(a.y,w.y,s1);
      s2 = fmaf(a.z,w.z,s2); s3 = fmaf(a.w,w.w,s3);
    }
    out[bG*Cn + cc] = (s0+s1)+(s2+s3) + bfc[cc];
  }
}

extern "C" void kernel_launch(void* const* d_in, const int* in_sizes, int n_in,
                              void* d_out, int out_size, void* d_ws, size_t ws_size,
                              hipStream_t stream) {
  const float* x    = (const float*)d_in[0];
  const float* mask = (const float*)d_in[1];
  const float* Wa   = (const float*)d_in[2];
  const float* ba   = (const float*)d_in[3];
  const float* Wih  = (const float*)d_in[4];
  const float* Whh  = (const float*)d_in[5];
  const float* bih  = (const float*)d_in[6];
  const float* bhh  = (const float*)d_in[7];
  const float* Wfc  = (const float*)d_in[8];
  const float* bfc  = (const float*)d_in[9];
  float* out = (float*)d_out;
  float* ws  = (float*)d_ws;

  // reset counters + h/score buffers every launch (deterministic replay)
  hipMemsetAsync(d_ws, 0, (size_t)WS_FLOATS * sizeof(float), stream);

  (void)hipFuncSetAttribute((const void*)fused_att_lstm,
                            hipFuncAttributeMaxDynamicSharedMemorySize, LDS_BYTES);

  void* args[] = { (void*)&x, (void*)&mask, (void*)&Wa, (void*)&ba,
                   (void*)&Wih, (void*)&Whh, (void*)&bih, (void*)&bhh,
                   (void*)&Wfc, (void*)&bfc, (void*)&out, (void*)&ws };
  hipLaunchCooperativeKernel((void*)fused_att_lstm, dim3(NWG), dim3(TPB),
                             args, LDS_BYTES, stream);
}

// Round 13
// 9941.088 us; speedup vs baseline: 2.5556x; 1.1337x over previous
//
#include <hip/hip_runtime.h>

typedef unsigned long long ull;

#define NWG   256
#define TPB   256
#define Bsz   128
#define Tlen  512
#define Pn    10
#define In    50
#define Hn    512
#define Cn    8
#define KTOT  562          // 512 (h) + 50 (emb)
#define KPAD  576          // padded; 144 float4 (multiple of 8 for XOR swizzle)
#define KF4   144
#define BSL   32           // batch rows per group
#define GRPW  64           // j-WGs per batch group

// sc-coherent (agent-scope relaxed) accessors — compiler-generated, correctly
// ordered vs barriers (R7-proven correct with ZERO fences).
#define AS(p,v)  __hip_atomic_store((p), (v), __ATOMIC_RELAXED, __HIP_MEMORY_SCOPE_AGENT)
#define ALU(p)   __hip_atomic_load((p),  __ATOMIC_RELAXED, __HIP_MEMORY_SCOPE_AGENT)

// ---- workspace layout (floats) ----
#define OFF_H   1024                   // u32[0..255]: 4 groups x {cnt, gen}
#define HBUF_N  (2*Bsz*Hn)
#define OFF_S   (OFF_H + HBUF_N)
#define SROW    12
#define SBUF_N  (3*Bsz*SROW)
#define WS_FLOATS (OFF_S + SBUF_N)

// ---- LDS layout (floats) ---- (identical to R3/R9)
#define L_SW     0                     // [32][KPAD] gate rows (swizzled)
#define L_SH     (32*KPAD)             // [32][KPAD] [h | emb | pad] (swizzled)
#define L_SCR    (2*32*KPAD)           // 3072: attn[32*10] | partialsT[3*16*64] | u[32*51]
#define L_SWA    (L_SCR + 3072)        // [8][51], col 50 = ba
#define L_BIAS   (L_SWA + 408)         // [32]
#define L_HNEW   (L_BIAS + 32)         // [8][33]  hnew[jj][b]
#define LDS_FLOATS (L_HNEW + 264)      // 40640 floats = 162560 B
#define LDS_BYTES  (LDS_FLOATS*4)

union UF2 { ull u; float2 f; };

extern "C" __global__ void __launch_bounds__(TPB, 1) fused_att_lstm(
    const float* __restrict__ x,   const float* __restrict__ mask,
    const float* __restrict__ Wa,  const float* __restrict__ ba,
    const float* __restrict__ Wih, const float* __restrict__ Whh,
    const float* __restrict__ bih, const float* __restrict__ bhh,
    const float* __restrict__ Wfc, const float* __restrict__ bfc,
    float* __restrict__ out, float* __restrict__ ws)
{
  extern __shared__ __align__(16) float lds[];
  float* sW    = lds + L_SW;
  float* sH    = lds + L_SH;
  float* sScr  = lds + L_SCR;    // attn / partialsT / u (disjoint lifetimes)
  float* sWa   = lds + L_SWA;
  float* sBias = lds + L_BIAS;
  float* sHnew = lds + L_HNEW;

  const int tid = threadIdx.x;
  const int wg  = blockIdx.x;
  const int jw  = wg & 63;
  const int grp = wg >> 6;
  const int bG0 = grp * BSL;
  const int jG0 = jw * 8;

  unsigned* cnt = reinterpret_cast<unsigned*>(ws) + grp*64;
  unsigned* gen = cnt + 16;
  float* hbuf = ws + OFF_H;        // [2][B][H]
  float* Sbuf = ws + OFF_S;        // [3][B][SROW]

  // ---- load resident weights (swizzled store: f4idx ^= (row>>2)&7) ----
  for (int idx = tid; idx < 32*KPAD; idx += TPB) {
    int r = idx / KPAD, k = idx - r*KPAD;
    int jj = r >> 2, g = r & 3;
    int grow = g*Hn + jG0 + jj;    // torch gate order i,f,g,o
    float v = 0.f;
    if (k < Hn)        v = Whh[grow*Hn + k];
    else if (k < KTOT) v = Wih[grow*In + (k - Hn)];
    sW[r*KPAD + (((((k>>2) ^ ((r>>2)&7))) << 2) | (k & 3))] = v;
  }
  for (int idx = tid; idx < 8*51; idx += TPB) {
    int jj = idx / 51, i = idx - jj*51;
    sWa[idx] = (i < In) ? Wa[(jG0+jj)*In + i] : ba[jG0+jj];
  }
  if (tid < 32) {
    int jj = tid >> 2, g = tid & 3;
    int grow = g*Hn + jG0 + jj;
    sBias[tid] = bih[grow] + bhh[grow];
  }
  if (tid < 32) {                          // zero pad cols 562..575 of sH once
    for (int k = KTOT; k < KPAD; ++k)
      sH[tid*KPAD + (((((k>>2) ^ ((tid>>2)&7))) << 2) | (k & 3))] = 0.f;
  }
  __syncthreads();

  const int kg = tid >> 6;                 // k-split group (wave index)
  const int tb = (tid >> 3) & 7;           // batch-tile (4 rows: 4tb..4tb+3)
  const int tr = tid & 7;                  // gate-row tile (rows 4tr..4tr+3 = jj=tr)
  const int lane = tid & 63;
  float cr[4] = {0.f, 0.f, 0.f, 0.f};      // cell state (kg0 threads: 4 cells)
  unsigned bgen = 0;

  for (int t = 0; t < Tlen; ++t) {
    const float* hprev = hbuf + ((t+1)&1)*Bsz*Hn;
    float*       hcur  = hbuf + (t&1)*Bsz*Hn;
    const float* Scur  = Sbuf + (t%3)*Bsz*SROW;
    float*       Snext = Sbuf + ((t+1)%3)*Bsz*SROW;
    float*       Szero = Sbuf + ((t+2)%3)*Bsz*SROW;

    // ---- A: h tile via chunked sc loads (R7 mapping; 16 VGPR transient) ----
    {
      const ull* src = reinterpret_cast<const ull*>(hprev + (size_t)bG0*Hn);
      #pragma unroll
      for (int c = 0; c < 4; ++c) {
        ull hb[8];
        #pragma unroll
        for (int j = 0; j < 8; ++j)
          hb[j] = ALU(&src[(c*8+j)*TPB + tid]);
        #pragma unroll
        for (int j = 0; j < 8; ++j) {
          int f = (c*8+j)*TPB + tid;       // 0..8191 (32 rows x 256 ull)
          int b = f >> 8, kd = f & 255;
          int kf = kd >> 1;
          int fi = b*KPAD + (((kf ^ ((b>>2)&7))) << 2) + (kd & 1)*2;
          UF2 cv; cv.u = hb[j];
          *reinterpret_cast<float2*>(&sH[fi]) = cv.f;
        }
      }
    }
    // score row via sc loads (R7-proven); mask cached (read-only, stays warm)
    float sreg[Pn], mreg[Pn];
    if (tid < BSL) {
      const float* srow = Scur + (size_t)(bG0+tid)*SROW;
      const float* mrow = mask + ((size_t)(bG0+tid)*Tlen + t)*Pn*In;
      #pragma unroll
      for (int p = 0; p < Pn; ++p) { sreg[p] = ALU(&srow[p]); mreg[p] = mrow[p*In]; }
    }
    if (tid < 6) AS(&Szero[bG0*SROW + jw*6 + tid], 0.f);

    // x-hoist for B (cached reads; L2-warm from E2's touch at step t-1 —
    // nothing ever invalidates L2 in this kernel)
    float xh0[Pn], xh1[Pn], xh2[Pn], xh3[Pn], xh4[Pn], xh5[Pn], xh6[Pn];
#define HOIST(S, ARR) { int idx = tid + (S)*TPB; if (idx < BSL*In) {            \
      int b = idx / In, ic = idx - b*In;                                        \
      const float* xb = x + (((size_t)(bG0+b)*Tlen + t)*Pn)*In + ic;            \
      _Pragma("unroll") for (int p = 0; p < Pn; ++p) ARR[p] = xb[p*In]; } }
    HOIST(0, xh0) HOIST(1, xh1) HOIST(2, xh2) HOIST(3, xh3)
    HOIST(4, xh4) HOIST(5, xh5) HOIST(6, xh6)
#undef HOIST

    if (tid < BSL) {
      float sc[Pn]; float mx = -1e30f;
      #pragma unroll
      for (int p = 0; p < Pn; ++p) {
        float s = sreg[p];
        s = (mreg[p] > 0.f) ? s : -1e9f;
        sc[p] = s; mx = fmaxf(mx, s);
      }
      float den = 0.f;
      #pragma unroll
      for (int p = 0; p < Pn; ++p) { sc[p] = expf(sc[p] - mx); den += sc[p]; }
      float inv = 1.f / den;
      #pragma unroll
      for (int p = 0; p < Pn; ++p) sScr[tid*10 + p] = sc[p] * inv;  // attn
    }
    __syncthreads();

    // ---- B: emb[b,i] from hoisted regs (same FMA order as R3/R9) ----
#define BTASK(S, ARR) { int idx = tid + (S)*TPB; if (idx < BSL*In) {            \
      int b = idx / In, ic = idx - b*In;                                        \
      float e = 0.f;                                                            \
      _Pragma("unroll") for (int p = 0; p < Pn; ++p)                            \
        e = fmaf(sScr[b*10+p], ARR[p], e);                                      \
      int k = Hn + ic;                                                          \
      sH[b*KPAD + (((((k>>2) ^ ((b>>2)&7))) << 2) | (k & 3))] = e; } }
    BTASK(0, xh0) BTASK(1, xh1) BTASK(2, xh2) BTASK(3, xh3)
    BTASK(4, xh4) BTASK(5, xh5) BTASK(6, xh6)
#undef BTASK
    __syncthreads();

    // ---- C: gate GEMM 32x32, 4-way k-split, 4x4 tiles, conflict-free ----
    float acc[4][4];
    {
      #pragma unroll
      for (int i = 0; i < 4; ++i)
        #pragma unroll
        for (int j = 0; j < 4; ++j) acc[i][j] = 0.f;
      const float4* sH4 = reinterpret_cast<const float4*>(sH);
      const float4* sW4 = reinterpret_cast<const float4*>(sW);
      const int kbeg = kg*36, kend = kbeg + 36;
      for (int kc = kbeg; kc < kend; ++kc) {
        float4 hv[4], wv[4];
        #pragma unroll
        for (int i = 0; i < 4; ++i) hv[i] = sH4[(4*tb+i)*KF4 + (kc ^ tb)];
        #pragma unroll
        for (int j = 0; j < 4; ++j) wv[j] = sW4[(4*tr+j)*KF4 + (kc ^ tr)];
        #pragma unroll
        for (int i = 0; i < 4; ++i)
          #pragma unroll
          for (int j = 0; j < 4; ++j) {
            acc[i][j] = fmaf(hv[i].x, wv[j].x, acc[i][j]);
            acc[i][j] = fmaf(hv[i].y, wv[j].y, acc[i][j]);
            acc[i][j] = fmaf(hv[i].z, wv[j].z, acc[i][j]);
            acc[i][j] = fmaf(hv[i].w, wv[j].w, acc[i][j]);
          }
      }
      if (kg > 0) {                        // transposed partials: stride-4B lanes
        float* dst = sScr + (kg-1)*1024 + lane;
        #pragma unroll
        for (int q = 0; q < 16; ++q) dst[q*64] = acc[q>>2][q&3];
      }
    }
    __syncthreads();

    // ---- D: kg0 reduces partials + LSTM cells (c in registers) ----
    if (kg == 0) {
      #pragma unroll
      for (int i = 0; i < 4; ++i) {
        float gv[4];
        #pragma unroll
        for (int g = 0; g < 4; ++g) {
          int q = i*4 + g;
          float v = acc[i][g];
          v += sScr[0*1024 + q*64 + lane];
          v += sScr[1*1024 + q*64 + lane];
          v += sScr[2*1024 + q*64 + lane];
          gv[g] = v + sBias[4*tr + g];
        }
        float ig = 1.f/(1.f + expf(-gv[0]));
        float fg = 1.f/(1.f + expf(-gv[1]));
        float gc = tanhf(gv[2]);
        float og = 1.f/(1.f + expf(-gv[3]));
        cr[i] = fg*cr[i] + ig*gc;
        float hn = og * tanhf(cr[i]);
        int b = 4*tb + i;
        sHnew[tr*33 + b] = hn;
        AS(&hcur[(size_t)(bG0+b)*Hn + jG0 + tr], hn);   // sc store (at MALL by barrier)
      }
    }
    __syncthreads();

    // ---- E1: partial u[b,i] = sum_jj Wa[jj,i]*hnew[b,jj]  (col 50 = ba.h) ----
    if (t < Tlen-1) {
      for (int idx = tid; idx < BSL*51; idx += TPB) {
        int b = idx / 51, ic = idx - b*51;
        float v = 0.f;
        #pragma unroll
        for (int jj = 0; jj < 8; ++jj) v = fmaf(sWa[jj*51+ic], sHnew[jj*33+b], v);
        sScr[idx] = v;                     // u overlays partials (lifetime ok)
      }
    }
    __syncthreads();

    // ---- E2: partial scores s[b,p] = u50 + x_{t+1}.u ; 320 atomics/WG ----
    if (t < Tlen-1) {
      for (int pr = tid; pr < BSL*Pn; pr += TPB) {
        int b = pr / Pn, p = pr - b*Pn;
        const float2* xp = reinterpret_cast<const float2*>(
            x + (((size_t)(bG0+b)*Tlen + (t+1))*Pn + p)*In);
        const float* u = sScr + b*51;
        float s = u[50];
        #pragma unroll
        for (int k2 = 0; k2 < 25; ++k2) {
          float2 xv = xp[k2];
          s = fmaf(xv.x, u[2*k2],   s);
          s = fmaf(xv.y, u[2*k2+1], s);
        }
        atomicAdd(&Snext[(size_t)(bG0+b)*SROW + p], s);
      }
    }

    // ---- counter barrier, ZERO fences (all cross-step data MALL-coherent) ----
    ++bgen;
    __syncthreads();                       // every wave vmcnt-drained: sc stores
                                           // + atomics are at the coherence point
    if (tid == 0) {
      unsigned old = atomicAdd(cnt, 1u);
      if (old == bgen * (unsigned)GRPW - 1u) {
        AS(gen, bgen);
      } else {
        while (ALU(gen) < bgen) __builtin_amdgcn_s_sleep(2);
      }
    }
    __syncthreads();
  }

  // ---- one-time fence (invalidate stale lines from prior graph replay) ----
  __syncthreads();
  if (tid == 0) __threadfence();
  __syncthreads();

  // ---- final classifier (jw==0 WG of each group) ----
  if (jw == 0) {
    const float* hfin = hbuf + ((Tlen-1)&1)*Bsz*Hn;
    int b = tid >> 3, cc = tid & 7;
    int bG = bG0 + b;
    const float4* hv = reinterpret_cast<const float4*>(hfin + (size_t)bG*Hn);
    const float4* wv = reinterpret_cast<const float4*>(Wfc + cc*Hn);
    float s0=0,s1=0,s2=0,s3=0;
    #pragma unroll 4
    for (int k = 0; k < Hn/4; ++k) {
      float4 a = hv[k], w = wv[k];
      s0 = fmaf(a.x,w.x,s0); s1 = fmaf(a.y,w.y,s1);
      s2 = fmaf(a.z,w.z,s2); s3 = fmaf(a.w,w.w,s3);
    }
    out[bG*Cn + cc] = (s0+s1)+(s2+s3) + bfc[cc];
  }
}

extern "C" void kernel_launch(void* const* d_in, const int* in_sizes, int n_in,
                              void* d_out, int out_size, void* d_ws, size_t ws_size,
                              hipStream_t stream) {
  const float* x    = (const float*)d_in[0];
  const float* mask = (const float*)d_in[1];
  const float* Wa   = (const float*)d_in[2];
  const float* ba   = (const float*)d_in[3];
  const float* Wih  = (const float*)d_in[4];
  const float* Whh  = (const float*)d_in[5];
  const float* bih  = (const float*)d_in[6];
  const float* bhh  = (const float*)d_in[7];
  const float* Wfc  = (const float*)d_in[8];
  const float* bfc  = (const float*)d_in[9];
  float* out = (float*)d_out;
  float* ws  = (float*)d_ws;

  // reset counters + h/score buffers every launch (deterministic replay)
  hipMemsetAsync(d_ws, 0, (size_t)WS_FLOATS * sizeof(float), stream);

  (void)hipFuncSetAttribute((const void*)fused_att_lstm,
                            hipFuncAttributeMaxDynamicSharedMemorySize, LDS_BYTES);

  void* args[] = { (void*)&x, (void*)&mask, (void*)&Wa, (void*)&ba,
                   (void*)&Wih, (void*)&Whh, (void*)&bih, (void*)&bhh,
                   (void*)&Wfc, (void*)&bfc, (void*)&out, (void*)&ws };
  hipLaunchCooperativeKernel((void*)fused_att_lstm, dim3(NWG), dim3(TPB),
                             args, LDS_BYTES, stream);
}

// Round 14
// 9126.337 us; speedup vs baseline: 2.7838x; 1.0893x over previous
//
#include <hip/hip_runtime.h>

typedef unsigned long long ull;

#define NWG   256
#define TPB   256
#define Bsz   128
#define Tlen  512
#define Pn    10
#define In    50
#define Hn    512
#define Cn    8
#define KTOT  562          // 512 (h) + 50 (emb)
#define KPAD  576          // padded; 144 float4 (multiple of 8 for XOR swizzle)
#define KF4   144
#define BSL   32           // batch rows per group
#define GRPW  64           // j-WGs per batch group
#define NCPY  4            // shadow score copies (atomic fan-in 64 -> 16)

// sc-coherent (agent-scope relaxed) accessors (R7/R13-proven)
#define AS(p,v)  __hip_atomic_store((p), (v), __ATOMIC_RELAXED, __HIP_MEMORY_SCOPE_AGENT)
#define ALU(p)   __hip_atomic_load((p),  __ATOMIC_RELAXED, __HIP_MEMORY_SCOPE_AGENT)

// ---- workspace layout (floats) ----
#define OFF_H   1024                   // u32[0..255]: 4 groups x {cnt, gen}
#define HBUF_N  (2*Bsz*Hn)
#define OFF_S   (OFF_H + HBUF_N)
#define SROW    12
#define CST     (Bsz*SROW)             // copy stride (1536)
#define SLICE   (NCPY*CST)             // per-rotation slice (6144)
#define SBUF_N  (3*SLICE)
#define WS_FLOATS (OFF_S + SBUF_N)

// ---- LDS layout (floats) ---- (identical to R3/R9/R13)
#define L_SW     0                     // [32][KPAD] gate rows (swizzled)
#define L_SH     (32*KPAD)             // [32][KPAD] [h | emb | pad] (swizzled)
#define L_SCR    (2*32*KPAD)           // 3072: attn[32*10] | partialsT[3*16*64] | u[32*51]
#define L_SWA    (L_SCR + 3072)        // [8][51], col 50 = ba
#define L_BIAS   (L_SWA + 408)         // [32]
#define L_HNEW   (L_BIAS + 32)         // [8][33]  hnew[jj][b]
#define LDS_FLOATS (L_HNEW + 264)      // 40640 floats = 162560 B
#define LDS_BYTES  (LDS_FLOATS*4)

union UF2 { ull u; float2 f; };

extern "C" __global__ void __launch_bounds__(TPB, 1) fused_att_lstm(
    const float* __restrict__ x,   const float* __restrict__ mask,
    const float* __restrict__ Wa,  const float* __restrict__ ba,
    const float* __restrict__ Wih, const float* __restrict__ Whh,
    const float* __restrict__ bih, const float* __restrict__ bhh,
    const float* __restrict__ Wfc, const float* __restrict__ bfc,
    float* __restrict__ out, float* __restrict__ ws)
{
  extern __shared__ __align__(16) float lds[];
  float* sW    = lds + L_SW;
  float* sH    = lds + L_SH;
  float* sScr  = lds + L_SCR;    // attn / partialsT / u (disjoint lifetimes)
  float* sWa   = lds + L_SWA;
  float* sBias = lds + L_BIAS;
  float* sHnew = lds + L_HNEW;

  const int tid = threadIdx.x;
  const int wg  = blockIdx.x;
  const int jw  = wg & 63;
  const int grp = wg >> 6;
  const int bG0 = grp * BSL;
  const int jG0 = jw * 8;

  unsigned* cnt = reinterpret_cast<unsigned*>(ws) + grp*64;
  unsigned* gen = cnt + 16;
  float* hbuf = ws + OFF_H;        // [2][B][H]
  float* Sbuf = ws + OFF_S;        // [3][NCPY][B][SROW]

  // ---- load resident weights (swizzled store: f4idx ^= (row>>2)&7) ----
  for (int idx = tid; idx < 32*KPAD; idx += TPB) {
    int r = idx / KPAD, k = idx - r*KPAD;
    int jj = r >> 2, g = r & 3;
    int grow = g*Hn + jG0 + jj;    // torch gate order i,f,g,o
    float v = 0.f;
    if (k < Hn)        v = Whh[grow*Hn + k];
    else if (k < KTOT) v = Wih[grow*In + (k - Hn)];
    sW[r*KPAD + (((((k>>2) ^ ((r>>2)&7))) << 2) | (k & 3))] = v;
  }
  for (int idx = tid; idx < 8*51; idx += TPB) {
    int jj = idx / 51, i = idx - jj*51;
    sWa[idx] = (i < In) ? Wa[(jG0+jj)*In + i] : ba[jG0+jj];
  }
  if (tid < 32) {
    int jj = tid >> 2, g = tid & 3;
    int grow = g*Hn + jG0 + jj;
    sBias[tid] = bih[grow] + bhh[grow];
  }
  if (tid < 32) {                          // zero pad cols 562..575 of sH once
    for (int k = KTOT; k < KPAD; ++k)
      sH[tid*KPAD + (((((k>>2) ^ ((tid>>2)&7))) << 2) | (k & 3))] = 0.f;
  }
  __syncthreads();

  const int kg = tid >> 6;                 // k-split group (wave index)
  const int tb = (tid >> 3) & 7;           // batch-tile (4 rows: 4tb..4tb+3)
  const int tr = tid & 7;                  // gate-row tile (rows 4tr..4tr+3 = jj=tr)
  const int lane = tid & 63;
  float cr[4] = {0.f, 0.f, 0.f, 0.f};      // cell state (kg0 threads: 4 cells)
  unsigned bgen = 0;

  for (int t = 0; t < Tlen; ++t) {
    const float* hprev = hbuf + ((t+1)&1)*Bsz*Hn;
    float*       hcur  = hbuf + (t&1)*Bsz*Hn;
    const float* Scur  = Sbuf + (t%3)*SLICE;
    float*       Snext = Sbuf + ((t+1)%3)*SLICE + (jw&(NCPY-1))*CST;
    float*       Szero = Sbuf + ((t+2)%3)*SLICE;

    // ---- A: h tile via 2x16 chunked sc loads (R7 mapping, transient regs) ----
    {
      const ull* src = reinterpret_cast<const ull*>(hprev + (size_t)bG0*Hn);
      #pragma unroll
      for (int c = 0; c < 2; ++c) {
        ull hb[16];
        #pragma unroll
        for (int j = 0; j < 16; ++j)
          hb[j] = ALU(&src[(c*16+j)*TPB + tid]);
        #pragma unroll
        for (int j = 0; j < 16; ++j) {
          int f = (c*16+j)*TPB + tid;      // 0..8191 (32 rows x 256 ull)
          int b = f >> 8, kd = f & 255;
          int kf = kd >> 1;
          int fi = b*KPAD + (((kf ^ ((b>>2)&7))) << 2) + (kd & 1)*2;
          UF2 cv; cv.u = hb[j];
          *reinterpret_cast<float2*>(&sH[fi]) = cv.f;
        }
      }
    }
    // score row: sum the NCPY shadow copies via sc loads; mask cached
    float sreg[Pn], mreg[Pn];
    if (tid < BSL) {
      const float* srow = Scur + (size_t)(bG0+tid)*SROW;
      const float* mrow = mask + ((size_t)(bG0+tid)*Tlen + t)*Pn*In;
      #pragma unroll
      for (int p = 0; p < Pn; ++p) {
        float s0 = ALU(&srow[p]);
        float s1 = ALU(&srow[CST + p]);
        float s2 = ALU(&srow[2*CST + p]);
        float s3 = ALU(&srow[3*CST + p]);
        sreg[p] = (s0 + s1) + (s2 + s3);
        mreg[p] = mrow[p*In];
      }
    }
    // zero the step-(t+2) slice: all NCPY copies, this group's 1536 floats
    if (tid < 24) {
      int idx = jw*24 + tid;               // [0,1536) across 64 WGs
      int c = idx / 384, w = idx - c*384;
      AS(&Szero[c*CST + bG0*SROW + w], 0.f);
    }

    // x-hoist for B (cached; L2-warm from E2's touch at step t-1)
    float xh0[Pn], xh1[Pn], xh2[Pn], xh3[Pn], xh4[Pn], xh5[Pn], xh6[Pn];
#define HOIST(S, ARR) { int idx = tid + (S)*TPB; if (idx < BSL*In) {            \
      int b = idx / In, ic = idx - b*In;                                        \
      const float* xb = x + (((size_t)(bG0+b)*Tlen + t)*Pn)*In + ic;            \
      _Pragma("unroll") for (int p = 0; p < Pn; ++p) ARR[p] = xb[p*In]; } }
    HOIST(0, xh0) HOIST(1, xh1) HOIST(2, xh2) HOIST(3, xh3)
    HOIST(4, xh4) HOIST(5, xh5) HOIST(6, xh6)
#undef HOIST

    if (tid < BSL) {
      float sc[Pn]; float mx = -1e30f;
      #pragma unroll
      for (int p = 0; p < Pn; ++p) {
        float s = sreg[p];
        s = (mreg[p] > 0.f) ? s : -1e9f;
        sc[p] = s; mx = fmaxf(mx, s);
      }
      float den = 0.f;
      #pragma unroll
      for (int p = 0; p < Pn; ++p) { sc[p] = expf(sc[p] - mx); den += sc[p]; }
      float inv = 1.f / den;
      #pragma unroll
      for (int p = 0; p < Pn; ++p) sScr[tid*10 + p] = sc[p] * inv;  // attn
    }
    __syncthreads();

    // ---- B: emb[b,i] from hoisted regs (same FMA order as R3/R9/R13) ----
#define BTASK(S, ARR) { int idx = tid + (S)*TPB; if (idx < BSL*In) {            \
      int b = idx / In, ic = idx - b*In;                                        \
      float e = 0.f;                                                            \
      _Pragma("unroll") for (int p = 0; p < Pn; ++p)                            \
        e = fmaf(sScr[b*10+p], ARR[p], e);                                      \
      int k = Hn + ic;                                                          \
      sH[b*KPAD + (((((k>>2) ^ ((b>>2)&7))) << 2) | (k & 3))] = e; } }
    BTASK(0, xh0) BTASK(1, xh1) BTASK(2, xh2) BTASK(3, xh3)
    BTASK(4, xh4) BTASK(5, xh5) BTASK(6, xh6)
#undef BTASK
    __syncthreads();

    // ---- C: gate GEMM 32x32, 4-way k-split, 4x4 tiles, conflict-free ----
    float acc[4][4];
    {
      #pragma unroll
      for (int i = 0; i < 4; ++i)
        #pragma unroll
        for (int j = 0; j < 4; ++j) acc[i][j] = 0.f;
      const float4* sH4 = reinterpret_cast<const float4*>(sH);
      const float4* sW4 = reinterpret_cast<const float4*>(sW);
      const int kbeg = kg*36, kend = kbeg + 36;
      for (int kc = kbeg; kc < kend; ++kc) {
        float4 hv[4], wv[4];
        #pragma unroll
        for (int i = 0; i < 4; ++i) hv[i] = sH4[(4*tb+i)*KF4 + (kc ^ tb)];
        #pragma unroll
        for (int j = 0; j < 4; ++j) wv[j] = sW4[(4*tr+j)*KF4 + (kc ^ tr)];
        #pragma unroll
        for (int i = 0; i < 4; ++i)
          #pragma unroll
          for (int j = 0; j < 4; ++j) {
            acc[i][j] = fmaf(hv[i].x, wv[j].x, acc[i][j]);
            acc[i][j] = fmaf(hv[i].y, wv[j].y, acc[i][j]);
            acc[i][j] = fmaf(hv[i].z, wv[j].z, acc[i][j]);
            acc[i][j] = fmaf(hv[i].w, wv[j].w, acc[i][j]);
          }
      }
      if (kg > 0) {                        // transposed partials: stride-4B lanes
        float* dst = sScr + (kg-1)*1024 + lane;
        #pragma unroll
        for (int q = 0; q < 16; ++q) dst[q*64] = acc[q>>2][q&3];
      }
    }
    __syncthreads();

    // ---- D: kg0 reduces partials + LSTM cells (c in registers) ----
    if (kg == 0) {
      #pragma unroll
      for (int i = 0; i < 4; ++i) {
        float gv[4];
        #pragma unroll
        for (int g = 0; g < 4; ++g) {
          int q = i*4 + g;
          float v = acc[i][g];
          v += sScr[0*1024 + q*64 + lane];
          v += sScr[1*1024 + q*64 + lane];
          v += sScr[2*1024 + q*64 + lane];
          gv[g] = v + sBias[4*tr + g];
        }
        float ig = 1.f/(1.f + expf(-gv[0]));
        float fg = 1.f/(1.f + expf(-gv[1]));
        float gc = tanhf(gv[2]);
        float og = 1.f/(1.f + expf(-gv[3]));
        cr[i] = fg*cr[i] + ig*gc;
        float hn = og * tanhf(cr[i]);
        int b = 4*tb + i;
        sHnew[tr*33 + b] = hn;
        AS(&hcur[(size_t)(bG0+b)*Hn + jG0 + tr], hn);   // sc store (at MALL by barrier)
      }
    }
    __syncthreads();

    // ---- E1: partial u[b,i] = sum_jj Wa[jj,i]*hnew[b,jj]  (col 50 = ba.h) ----
    if (t < Tlen-1) {
      for (int idx = tid; idx < BSL*51; idx += TPB) {
        int b = idx / 51, ic = idx - b*51;
        float v = 0.f;
        #pragma unroll
        for (int jj = 0; jj < 8; ++jj) v = fmaf(sWa[jj*51+ic], sHnew[jj*33+b], v);
        sScr[idx] = v;                     // u overlays partials (lifetime ok)
      }
    }
    __syncthreads();

    // ---- E2: partial scores; atomics into shadow copy jw&3 (fan-in 16) ----
    if (t < Tlen-1) {
      for (int pr = tid; pr < BSL*Pn; pr += TPB) {
        int b = pr / Pn, p = pr - b*Pn;
        const float2* xp = reinterpret_cast<const float2*>(
            x + (((size_t)(bG0+b)*Tlen + (t+1))*Pn + p)*In);
        const float* u = sScr + b*51;
        float s = u[50];
        #pragma unroll
        for (int k2 = 0; k2 < 25; ++k2) {
          float2 xv = xp[k2];
          s = fmaf(xv.x, u[2*k2],   s);
          s = fmaf(xv.y, u[2*k2+1], s);
        }
        atomicAdd(&Snext[(size_t)(bG0+b)*SROW + p], s);
      }
    }

    // ---- counter barrier, ZERO fences (all cross-step data MALL-coherent) ----
    ++bgen;
    __syncthreads();                       // every wave vmcnt-drained: sc stores
                                           // + atomics are at the coherence point
    if (tid == 0) {
      unsigned old = atomicAdd(cnt, 1u);
      if (old == bgen * (unsigned)GRPW - 1u) {
        AS(gen, bgen);
      } else {
        while (ALU(gen) < bgen) __builtin_amdgcn_s_sleep(1);
      }
    }
    __syncthreads();
  }

  // ---- one-time fence (invalidate stale lines from prior graph replay) ----
  __syncthreads();
  if (tid == 0) __threadfence();
  __syncthreads();

  // ---- final classifier (jw==0 WG of each group) ----
  if (jw == 0) {
    const float* hfin = hbuf + ((Tlen-1)&1)*Bsz*Hn;
    int b = tid >> 3, cc = tid & 7;
    int bG = bG0 + b;
    const float4* hv = reinterpret_cast<const float4*>(hfin + (size_t)bG*Hn);
    const float4* wv = reinterpret_cast<const float4*>(Wfc + cc*Hn);
    float s0=0,s1=0,s2=0,s3=0;
    #pragma unroll 4
    for (int k = 0; k < Hn/4; ++k) {
      float4 a = hv[k], w = wv[k];
      s0 = fmaf(a.x,w.x,s0); s1 = fmaf(a.y,w.y,s1);
      s2 = fmaf(a.z,w.z,s2); s3 = fmaf(a.w,w.w,s3);
    }
    out[bG*Cn + cc] = (s0+s1)+(s2+s3) + bfc[cc];
  }
}

extern "C" void kernel_launch(void* const* d_in, const int* in_sizes, int n_in,
                              void* d_out, int out_size, void* d_ws, size_t ws_size,
                              hipStream_t stream) {
  const float* x    = (const float*)d_in[0];
  const float* mask = (const float*)d_in[1];
  const float* Wa   = (const float*)d_in[2];
  const float* ba   = (const float*)d_in[3];
  const float* Wih  = (const float*)d_in[4];
  const float* Whh  = (const float*)d_in[5];
  const float* bih  = (const float*)d_in[6];
  const float* bhh  = (const float*)d_in[7];
  const float* Wfc  = (const float*)d_in[8];
  const float* bfc  = (const float*)d_in[9];
  float* out = (float*)d_out;
  float* ws  = (float*)d_ws;

  // reset counters + h/score buffers every launch (deterministic replay)
  hipMemsetAsync(d_ws, 0, (size_t)WS_FLOATS * sizeof(float), stream);

  (void)hipFuncSetAttribute((const void*)fused_att_lstm,
                            hipFuncAttributeMaxDynamicSharedMemorySize, LDS_BYTES);

  void* args[] = { (void*)&x, (void*)&mask, (void*)&Wa, (void*)&ba,
                   (void*)&Wih, (void*)&Whh, (void*)&bih, (void*)&bhh,
                   (void*)&Wfc, (void*)&bfc, (void*)&out, (void*)&ws };
  hipLaunchCooperativeKernel((void*)fused_att_lstm, dim3(NWG), dim3(TPB),
                             args, LDS_BYTES, stream);
}

// Round 15
// 8975.779 us; speedup vs baseline: 2.8304x; 1.0168x over previous
//
#include <hip/hip_runtime.h>

typedef unsigned long long ull;

#define NWG   256
#define TPB   256
#define Bsz   128
#define Tlen  512
#define Pn    10
#define In    50
#define Hn    512
#define Cn    8
#define KTOT  562          // 512 (h) + 50 (emb)
#define KPAD  576          // padded; 144 float4 (multiple of 8 for XOR swizzle)
#define KF4   144
#define BSL   32           // batch rows per group
#define GRPW  64           // j-WGs per batch group
#define NCPY  4            // shadow score copies (atomic fan-in 64 -> 16)

// sc-coherent (agent-scope relaxed) accessors (R7/R13/R14-proven)
#define AS(p,v)  __hip_atomic_store((p), (v), __ATOMIC_RELAXED, __HIP_MEMORY_SCOPE_AGENT)
#define ALU(p)   __hip_atomic_load((p),  __ATOMIC_RELAXED, __HIP_MEMORY_SCOPE_AGENT)

// ---- workspace layout (floats) ----
// [0..1023]: barrier region, 4 groups x 256 u32; per group:
//   sub[k] at +k*64 (k=0..3, 64B-separated), master at +16, gen at +32
#define OFF_H   1024
#define HBUF_N  (2*Bsz*Hn)
#define OFF_S   (OFF_H + HBUF_N)
#define SROW    12
#define CST     (Bsz*SROW)             // copy stride (1536)
#define SLICE   (NCPY*CST)             // per-rotation slice (6144)
#define SBUF_N  (3*SLICE)
#define WS_FLOATS (OFF_S + SBUF_N)

// ---- LDS layout (floats) ---- (identical to R3/R9/R13/R14)
#define L_SW     0                     // [32][KPAD] gate rows (swizzled)
#define L_SH     (32*KPAD)             // [32][KPAD] [h | emb | pad] (swizzled)
#define L_SCR    (2*32*KPAD)           // 3072: attn[32*10] | partialsT[3*16*64] | u[32*51]
#define L_SWA    (L_SCR + 3072)        // [8][51], col 50 = ba
#define L_BIAS   (L_SWA + 408)         // [32]
#define L_HNEW   (L_BIAS + 32)         // [8][33]  hnew[jj][b]
#define LDS_FLOATS (L_HNEW + 264)      // 40640 floats = 162560 B
#define LDS_BYTES  (LDS_FLOATS*4)

union UF2 { ull u; float2 f; };

extern "C" __global__ void __launch_bounds__(TPB, 1) fused_att_lstm(
    const float* __restrict__ x,   const float* __restrict__ mask,
    const float* __restrict__ Wa,  const float* __restrict__ ba,
    const float* __restrict__ Wih, const float* __restrict__ Whh,
    const float* __restrict__ bih, const float* __restrict__ bhh,
    const float* __restrict__ Wfc, const float* __restrict__ bfc,
    float* __restrict__ out, float* __restrict__ ws)
{
  extern __shared__ __align__(16) float lds[];
  float* sW    = lds + L_SW;
  float* sH    = lds + L_SH;
  float* sScr  = lds + L_SCR;    // attn / partialsT / u (disjoint lifetimes)
  float* sWa   = lds + L_SWA;
  float* sBias = lds + L_BIAS;
  float* sHnew = lds + L_HNEW;

  const int tid = threadIdx.x;
  const int wg  = blockIdx.x;
  const int jw  = wg & 63;
  const int grp = wg >> 6;
  const int bG0 = grp * BSL;
  const int jG0 = jw * 8;

  unsigned* bar = reinterpret_cast<unsigned*>(ws) + grp*256;  // two-level barrier
  float* hbuf = ws + OFF_H;        // [2][B][H]
  float* Sbuf = ws + OFF_S;        // [3][NCPY][B][SROW]

  // ---- load resident weights (swizzled store: f4idx ^= (row>>2)&7) ----
  for (int idx = tid; idx < 32*KPAD; idx += TPB) {
    int r = idx / KPAD, k = idx - r*KPAD;
    int jj = r >> 2, g = r & 3;
    int grow = g*Hn + jG0 + jj;    // torch gate order i,f,g,o
    float v = 0.f;
    if (k < Hn)        v = Whh[grow*Hn + k];
    else if (k < KTOT) v = Wih[grow*In + (k - Hn)];
    sW[r*KPAD + (((((k>>2) ^ ((r>>2)&7))) << 2) | (k & 3))] = v;
  }
  for (int idx = tid; idx < 8*51; idx += TPB) {
    int jj = idx / 51, i = idx - jj*51;
    sWa[idx] = (i < In) ? Wa[(jG0+jj)*In + i] : ba[jG0+jj];
  }
  if (tid < 32) {
    int jj = tid >> 2, g = tid & 3;
    int grow = g*Hn + jG0 + jj;
    sBias[tid] = bih[grow] + bhh[grow];
  }
  if (tid < 32) {                          // zero pad cols 562..575 of sH once
    for (int k = KTOT; k < KPAD; ++k)
      sH[tid*KPAD + (((((k>>2) ^ ((tid>>2)&7))) << 2) | (k & 3))] = 0.f;
  }
  __syncthreads();

  const int kg = tid >> 6;                 // k-split group (wave index)
  const int tb = (tid >> 3) & 7;           // batch-tile (4 rows: 4tb..4tb+3)
  const int tr = tid & 7;                  // gate-row tile (rows 4tr..4tr+3 = jj=tr)
  const int lane = tid & 63;
  float cr[4] = {0.f, 0.f, 0.f, 0.f};      // cell state (kg0 threads: 4 cells)
  unsigned bgen = 0;

  for (int t = 0; t < Tlen; ++t) {
    const float* hprev = hbuf + ((t+1)&1)*Bsz*Hn;
    float*       hcur  = hbuf + (t&1)*Bsz*Hn;
    const float* Scur  = Sbuf + (t%3)*SLICE;
    float*       Snext = Sbuf + ((t+1)%3)*SLICE + (jw&(NCPY-1))*CST;
    float*       Szero = Sbuf + ((t+2)%3)*SLICE;

    // ---- A: SCORE loads FIRST (oldest in vmcnt queue -> softmax waits only
    //         on them), then h chunks, then x-hoist; h latency overlaps ----
    float sreg[Pn], mreg[Pn];
    if (tid < BSL) {
      const float* srow = Scur + (size_t)(bG0+tid)*SROW;
      const float* mrow = mask + ((size_t)(bG0+tid)*Tlen + t)*Pn*In;
      #pragma unroll
      for (int p = 0; p < Pn; ++p) {
        float s0 = ALU(&srow[p]);
        float s1 = ALU(&srow[CST + p]);
        float s2 = ALU(&srow[2*CST + p]);
        float s3 = ALU(&srow[3*CST + p]);
        sreg[p] = (s0 + s1) + (s2 + s3);
        mreg[p] = mrow[p*In];
      }
    }
    // h tile via 2x16 chunked sc loads (R7 mapping, transient regs)
    {
      const ull* src = reinterpret_cast<const ull*>(hprev + (size_t)bG0*Hn);
      #pragma unroll
      for (int c = 0; c < 2; ++c) {
        ull hb[16];
        #pragma unroll
        for (int j = 0; j < 16; ++j)
          hb[j] = ALU(&src[(c*16+j)*TPB + tid]);
        #pragma unroll
        for (int j = 0; j < 16; ++j) {
          int f = (c*16+j)*TPB + tid;      // 0..8191 (32 rows x 256 ull)
          int b = f >> 8, kd = f & 255;
          int kf = kd >> 1;
          int fi = b*KPAD + (((kf ^ ((b>>2)&7))) << 2) + (kd & 1)*2;
          UF2 cv; cv.u = hb[j];
          *reinterpret_cast<float2*>(&sH[fi]) = cv.f;
        }
      }
    }
    // zero the step-(t+2) slice: all NCPY copies, this group's 1536 floats
    if (tid < 24) {
      int idx = jw*24 + tid;               // [0,1536) across 64 WGs
      int c = idx / 384, w = idx - c*384;
      AS(&Szero[c*CST + bG0*SROW + w], 0.f);
    }

    // x-hoist for B (cached; L2-warm from E2's touch at step t-1)
    float xh0[Pn], xh1[Pn], xh2[Pn], xh3[Pn], xh4[Pn], xh5[Pn], xh6[Pn];
#define HOIST(S, ARR) { int idx = tid + (S)*TPB; if (idx < BSL*In) {            \
      int b = idx / In, ic = idx - b*In;                                        \
      const float* xb = x + (((size_t)(bG0+b)*Tlen + t)*Pn)*In + ic;            \
      _Pragma("unroll") for (int p = 0; p < Pn; ++p) ARR[p] = xb[p*In]; } }
    HOIST(0, xh0) HOIST(1, xh1) HOIST(2, xh2) HOIST(3, xh3)
    HOIST(4, xh4) HOIST(5, xh5) HOIST(6, xh6)
#undef HOIST

    if (tid < BSL) {
      float sc[Pn]; float mx = -1e30f;
      #pragma unroll
      for (int p = 0; p < Pn; ++p) {
        float s = sreg[p];
        s = (mreg[p] > 0.f) ? s : -1e9f;
        sc[p] = s; mx = fmaxf(mx, s);
      }
      float den = 0.f;
      #pragma unroll
      for (int p = 0; p < Pn; ++p) { sc[p] = expf(sc[p] - mx); den += sc[p]; }
      float inv = 1.f / den;
      #pragma unroll
      for (int p = 0; p < Pn; ++p) sScr[tid*10 + p] = sc[p] * inv;  // attn
    }
    __syncthreads();

    // ---- B: emb[b,i] from hoisted regs (same FMA order as R3/R9/R13/R14) ----
#define BTASK(S, ARR) { int idx = tid + (S)*TPB; if (idx < BSL*In) {            \
      int b = idx / In, ic = idx - b*In;                                        \
      float e = 0.f;                                                            \
      _Pragma("unroll") for (int p = 0; p < Pn; ++p)                            \
        e = fmaf(sScr[b*10+p], ARR[p], e);                                      \
      int k = Hn + ic;                                                          \
      sH[b*KPAD + (((((k>>2) ^ ((b>>2)&7))) << 2) | (k & 3))] = e; } }
    BTASK(0, xh0) BTASK(1, xh1) BTASK(2, xh2) BTASK(3, xh3)
    BTASK(4, xh4) BTASK(5, xh5) BTASK(6, xh6)
#undef BTASK
    __syncthreads();

    // ---- C: gate GEMM 32x32, 4-way k-split, 4x4 tiles, conflict-free ----
    float acc[4][4];
    {
      #pragma unroll
      for (int i = 0; i < 4; ++i)
        #pragma unroll
        for (int j = 0; j < 4; ++j) acc[i][j] = 0.f;
      const float4* sH4 = reinterpret_cast<const float4*>(sH);
      const float4* sW4 = reinterpret_cast<const float4*>(sW);
      const int kbeg = kg*36, kend = kbeg + 36;
      for (int kc = kbeg; kc < kend; ++kc) {
        float4 hv[4], wv[4];
        #pragma unroll
        for (int i = 0; i < 4; ++i) hv[i] = sH4[(4*tb+i)*KF4 + (kc ^ tb)];
        #pragma unroll
        for (int j = 0; j < 4; ++j) wv[j] = sW4[(4*tr+j)*KF4 + (kc ^ tr)];
        #pragma unroll
        for (int i = 0; i < 4; ++i)
          #pragma unroll
          for (int j = 0; j < 4; ++j) {
            acc[i][j] = fmaf(hv[i].x, wv[j].x, acc[i][j]);
            acc[i][j] = fmaf(hv[i].y, wv[j].y, acc[i][j]);
            acc[i][j] = fmaf(hv[i].z, wv[j].z, acc[i][j]);
            acc[i][j] = fmaf(hv[i].w, wv[j].w, acc[i][j]);
          }
      }
      if (kg > 0) {                        // transposed partials: stride-4B lanes
        float* dst = sScr + (kg-1)*1024 + lane;
        #pragma unroll
        for (int q = 0; q < 16; ++q) dst[q*64] = acc[q>>2][q&3];
      }
    }
    __syncthreads();

    // ---- D: kg0 reduces partials + LSTM cells (c in registers) ----
    if (kg == 0) {
      #pragma unroll
      for (int i = 0; i < 4; ++i) {
        float gv[4];
        #pragma unroll
        for (int g = 0; g < 4; ++g) {
          int q = i*4 + g;
          float v = acc[i][g];
          v += sScr[0*1024 + q*64 + lane];
          v += sScr[1*1024 + q*64 + lane];
          v += sScr[2*1024 + q*64 + lane];
          gv[g] = v + sBias[4*tr + g];
        }
        float ig = 1.f/(1.f + expf(-gv[0]));
        float fg = 1.f/(1.f + expf(-gv[1]));
        float gc = tanhf(gv[2]);
        float og = 1.f/(1.f + expf(-gv[3]));
        cr[i] = fg*cr[i] + ig*gc;
        float hn = og * tanhf(cr[i]);
        int b = 4*tb + i;
        sHnew[tr*33 + b] = hn;
        AS(&hcur[(size_t)(bG0+b)*Hn + jG0 + tr], hn);   // sc store (at MALL by barrier)
      }
    }
    __syncthreads();

    // ---- E1: partial u[b,i] = sum_jj Wa[jj,i]*hnew[b,jj]  (col 50 = ba.h) ----
    if (t < Tlen-1) {
      for (int idx = tid; idx < BSL*51; idx += TPB) {
        int b = idx / 51, ic = idx - b*51;
        float v = 0.f;
        #pragma unroll
        for (int jj = 0; jj < 8; ++jj) v = fmaf(sWa[jj*51+ic], sHnew[jj*33+b], v);
        sScr[idx] = v;                     // u overlays partials (lifetime ok)
      }
    }
    __syncthreads();

    // ---- E2: partial scores; atomics into shadow copy jw&3 (fan-in 16) ----
    if (t < Tlen-1) {
      for (int pr = tid; pr < BSL*Pn; pr += TPB) {
        int b = pr / Pn, p = pr - b*Pn;
        const float2* xp = reinterpret_cast<const float2*>(
            x + (((size_t)(bG0+b)*Tlen + (t+1))*Pn + p)*In);
        const float* u = sScr + b*51;
        float s = u[50];
        #pragma unroll
        for (int k2 = 0; k2 < 25; ++k2) {
          float2 xv = xp[k2];
          s = fmaf(xv.x, u[2*k2],   s);
          s = fmaf(xv.y, u[2*k2+1], s);
        }
        atomicAdd(&Snext[(size_t)(bG0+b)*SROW + p], s);
      }
    }

    // ---- two-level counter barrier, ZERO fences ----
    // sub[jw&3] chain depth 16 -> master chain depth 4 -> gen release.
    ++bgen;
    __syncthreads();                       // every wave vmcnt-drained: sc stores
                                           // + atomics are at the coherence point
    if (tid == 0) {
      unsigned old = atomicAdd(&bar[(jw&3)*64], 1u);
      if (old == bgen*16u - 1u) {          // last arrival of this sub-group
        unsigned m = atomicAdd(&bar[16], 1u);
        if (m == bgen*4u - 1u) AS(&bar[32], bgen);
      }
      while (ALU(&bar[32]) < bgen) __builtin_amdgcn_s_sleep(1);
    }
    __syncthreads();
  }

  // ---- one-time fence (invalidate stale lines from prior graph replay) ----
  __syncthreads();
  if (tid == 0) __threadfence();
  __syncthreads();

  // ---- final classifier (jw==0 WG of each group) ----
  if (jw == 0) {
    const float* hfin = hbuf + ((Tlen-1)&1)*Bsz*Hn;
    int b = tid >> 3, cc = tid & 7;
    int bG = bG0 + b;
    const float4* hv = reinterpret_cast<const float4*>(hfin + (size_t)bG*Hn);
    const float4* wv = reinterpret_cast<const float4*>(Wfc + cc*Hn);
    float s0=0,s1=0,s2=0,s3=0;
    #pragma unroll 4
    for (int k = 0; k < Hn/4; ++k) {
      float4 a = hv[k], w = wv[k];
      s0 = fmaf(a.x,w.x,s0); s1 = fmaf(a.y,w.y,s1);
      s2 = fmaf(a.z,w.z,s2); s3 = fmaf(a.w,w.w,s3);
    }
    out[bG*Cn + cc] = (s0+s1)+(s2+s3) + bfc[cc];
  }
}

extern "C" void kernel_launch(void* const* d_in, const int* in_sizes, int n_in,
                              void* d_out, int out_size, void* d_ws, size_t ws_size,
                              hipStream_t stream) {
  const float* x    = (const float*)d_in[0];
  const float* mask = (const float*)d_in[1];
  const float* Wa   = (const float*)d_in[2];
  const float* ba   = (const float*)d_in[3];
  const float* Wih  = (const float*)d_in[4];
  const float* Whh  = (const float*)d_in[5];
  const float* bih  = (const float*)d_in[6];
  const float* bhh  = (const float*)d_in[7];
  const float* Wfc  = (const float*)d_in[8];
  const float* bfc  = (const float*)d_in[9];
  float* out = (float*)d_out;
  float* ws  = (float*)d_ws;

  // reset barrier region + h/score buffers every launch (deterministic replay)
  hipMemsetAsync(d_ws, 0, (size_t)WS_FLOATS * sizeof(float), stream);

  (void)hipFuncSetAttribute((const void*)fused_att_lstm,
                            hipFuncAttributeMaxDynamicSharedMemorySize, LDS_BYTES);

  void* args[] = { (void*)&x, (void*)&mask, (void*)&Wa, (void*)&ba,
                   (void*)&Wih, (void*)&Whh, (void*)&bih, (void*)&bhh,
                   (void*)&Wfc, (void*)&bfc, (void*)&out, (void*)&ws };
  hipLaunchCooperativeKernel((void*)fused_att_lstm, dim3(NWG), dim3(TPB),
                             args, LDS_BYTES, stream);
}